// Round 7
// baseline (1526.108 us; speedup 1.0000x reference)
//
#include <hip/hip_runtime.h>
#include <math.h>

// NeuroSAT RNN forward on MI355X — single persistent fused kernel.
// 256 blocks (1/CU), 4 blocks per graph, per-graph atomic barriers between
// LC/CL phases. Weights LDS-staged per phase (bf16x3 MFMA). Degree-sorted
// lane assignment kills CSR-gather divergence.
namespace {
constexpr int NVARS    = 256;
constexpr int LITS_PER = 2 * NVARS;     // 512
constexpr int Bg       = 64;            // graphs
constexpr int NL       = Bg * LITS_PER; // 32768 literals
constexpr int CLS_PER  = 1024;
constexpr int NC       = Bg * CLS_PER;  // 65536 clauses
constexpr int NE       = NC * 3;        // 196608 edges (K=3)
constexpr int D        = 128;
constexpr int T        = 8;             // num_iters (fixed scalar input)

// d_out flat layout (reference tuple order)
constexpr size_t OFF_VOTE  = 0;                                  // [NL]
constexpr size_t OFF_XL    = (size_t)NL;                         // [NL*D]   (x_l state)
constexpr size_t OFF_POOL  = OFF_XL + (size_t)NL * D;            // [Bg]
constexpr size_t OFF_TLAST = OFF_POOL + Bg;                      // [NL]
constexpr size_t OFF_TALL  = OFF_TLAST + NL;                     // [(T+1)*NL]
constexpr size_t OFF_CALL  = OFF_TALL + (size_t)(T + 1) * NL;    // [(T+1)*NC*D] (x_c state)
constexpr size_t OFF_T0    = OFF_CALL + (size_t)(T + 1) * NC * D;// [NL]

// packed weights: 5 logical DxD matrices, each hi plane (16384 us) + lo plane:
// 0: W_ih_lc | 1: W_hh_lc | 2: W_hh_cl | 3: W_ih_cl[:, :128] | 4: W_ih_cl[:, 128:]
constexpr int PKM    = 16384;           // ushorts per plane
constexpr int PK_TOT = 5 * 2 * PKM;
constexpr size_t SHM = 4 * PKM * sizeof(unsigned short) + 3072;  // 128 KB + scratch
} // namespace

typedef __attribute__((ext_vector_type(8))) short short8v;
typedef __attribute__((ext_vector_type(4))) float f32x4;

__device__ __forceinline__ unsigned short f2bf(float v) {
    unsigned u = __float_as_uint(v);
    return (unsigned short)((u + 0x7fffu + ((u >> 16) & 1u)) >> 16);  // RNE
}
__device__ __forceinline__ float bf2f(unsigned short b) {
    return __uint_as_float(((unsigned)b) << 16);
}
__device__ __forceinline__ void cvt_frag(const float (&v)[8], short8v& ah, short8v& al) {
    #pragma unroll
    for (int j = 0; j < 8; j++) {
        unsigned short h = f2bf(v[j]);
        ah[j] = (short)h;
        al[j] = (short)f2bf(v[j] - bf2f(h));
    }
}
__device__ __forceinline__ float ftanh(float x) {
    float e = __builtin_amdgcn_exp2f(x * 2.885390081777926814f);
    return 1.0f - 2.0f * __builtin_amdgcn_rcpf(e + 1.0f);
}
// bf16x3 dual-rowgroup MFMA site: B (hi+lo) from LDS, 6 MFMAs
__device__ __forceinline__ void mm3l(f32x4& c0, f32x4& c1,
                                     short8v a0h, short8v a0l, short8v a1h, short8v a1l,
                                     const unsigned short* buf, int off) {
    short8v bh = *(const short8v*)(buf + off);
    short8v bl = *(const short8v*)(buf + PKM + off);
    c0 = __builtin_amdgcn_mfma_f32_16x16x32_bf16(a0h, bh, c0, 0, 0, 0);
    c0 = __builtin_amdgcn_mfma_f32_16x16x32_bf16(a0h, bl, c0, 0, 0, 0);
    c0 = __builtin_amdgcn_mfma_f32_16x16x32_bf16(a0l, bh, c0, 0, 0, 0);
    c1 = __builtin_amdgcn_mfma_f32_16x16x32_bf16(a1h, bh, c1, 0, 0, 0);
    c1 = __builtin_amdgcn_mfma_f32_16x16x32_bf16(a1h, bl, c1, 0, 0, 0);
    c1 = __builtin_amdgcn_mfma_f32_16x16x32_bf16(a1l, bh, c1, 0, 0, 0);
}

// per-graph 4-block barrier: device-scope, XCD-placement-agnostic
__device__ __forceinline__ void gbar(int* ctr, int target) {
    __syncthreads();
    if (threadIdx.x == 0) {
        __threadfence();                 // release: publish this block's writes
        atomicAdd(ctr, 1);
        while (__hip_atomic_load(ctr, __ATOMIC_RELAXED, __HIP_MEMORY_SCOPE_AGENT) < target)
            __builtin_amdgcn_s_sleep(4);
        __threadfence();                 // acquire: see siblings' writes
    }
    __syncthreads();
}

// ---------------- W packing --------------------------------------------------
__global__ __launch_bounds__(256) void pack5(
    const float* __restrict__ ihlc, const float* __restrict__ hhlc,
    const float* __restrict__ hhcl, const float* __restrict__ ihcl,
    unsigned short* __restrict__ pk) {
    int idx = blockIdx.x * 256 + threadIdx.x;
    int mat = idx >> 14, rel = idx & 16383;
    int j = rel & 7, lane = (rel >> 3) & 63, ks = (rel >> 9) & 3, n = rel >> 11;
    int r = n * 16 + (lane & 15);
    int k = ks * 32 + (lane >> 4) * 8 + j;
    float w;
    if (mat == 0)      w = ihlc[r * 128 + k];
    else if (mat == 1) w = hhlc[r * 128 + k];
    else if (mat == 2) w = hhcl[r * 128 + k];
    else if (mat == 3) w = ihcl[r * 256 + k];
    else               w = ihcl[r * 256 + 128 + k];
    unsigned short h = f2bf(w);
    pk[mat * 2 * PKM + rel] = h;
    pk[mat * 2 * PKM + PKM + rel] = f2bf(w - bf2f(h));
}

// ---------------- CSR build --------------------------------------------------
__global__ void csr_count(const int* __restrict__ edge_lit, int* __restrict__ counts) {
    int e = blockIdx.x * blockDim.x + threadIdx.x;
    if (e < NE) atomicAdd(&counts[edge_lit[e]], 1);
}

__global__ __launch_bounds__(1024) void csr_scan(const int* __restrict__ counts,
                                                 int* __restrict__ offs,
                                                 int* __restrict__ cursor) {
    __shared__ int part[1024];
    const int t = threadIdx.x;
    const int base = t * 32;
    int local[32];
    int s = 0;
    for (int i = 0; i < 32; i++) { local[i] = s; s += counts[base + i]; }
    part[t] = s;
    __syncthreads();
    for (int d = 1; d < 1024; d <<= 1) {
        int v = 0;
        if (t >= d) v = part[t - d];
        __syncthreads();
        if (t >= d) part[t] += v;
        __syncthreads();
    }
    const int excl = (t == 0) ? 0 : part[t - 1];
    for (int i = 0; i < 32; i++) {
        int o = excl + local[i];
        offs[base + i] = o;
        cursor[base + i] = o;
    }
    if (t == 1023) offs[NL] = part[1023];
}

__global__ void csr_fill(const int* __restrict__ edge_lit, int* __restrict__ cursor,
                         int* __restrict__ csr) {
    int e = blockIdx.x * blockDim.x + threadIdx.x;
    if (e < NE) {
        int l = edge_lit[e];
        int p = atomicAdd(&cursor[l], 1);
        csr[p] = e / 3;
    }
}

__global__ void csr_sort(const int* __restrict__ offs, int* __restrict__ csr) {
    int l = blockIdx.x * blockDim.x + threadIdx.x;
    if (l >= NL) return;
    int s = offs[l], e = offs[l + 1];
    for (int i = s + 1; i < e; i++) {
        int v = csr[i];
        int j = i - 1;
        while (j >= s && csr[j] > v) { csr[j + 1] = csr[j]; j--; }
        csr[j + 1] = v;
    }
}

// per-128-literal-block degree sort (stable by index) -> perm of local indices
__global__ __launch_bounds__(128) void make_perm(const int* __restrict__ counts,
                                                 int* __restrict__ perm) {
    __shared__ int d[128];
    const int b = blockIdx.x, i = threadIdx.x;
    d[i] = counts[b * 128 + i];
    __syncthreads();
    const int di = d[i];
    int rank = 0;
    for (int j = 0; j < 128; j++) {
        int dj = d[j];
        rank += (dj < di) || (dj == di && j < i);
    }
    perm[b * 128 + rank] = i;
}

// -------- gather helpers -----------------------------------------------------
__device__ __forceinline__ void gather3(const int* __restrict__ ep,
                                        const float* __restrict__ xl, int arow, int g,
                                        float (&v)[4][8]) {
    int e0 = ep[3 * arow], e1 = ep[3 * arow + 1], e2 = ep[3 * arow + 2];
    const float* r0 = xl + (size_t)e0 * D + g * 8;
    const float* r1 = xl + (size_t)e1 * D + g * 8;
    const float* r2 = xl + (size_t)e2 * D + g * 8;
    #pragma unroll
    for (int ks = 0; ks < 4; ks++) {
        float4 a0 = *(const float4*)(r0 + ks * 32), a1 = *(const float4*)(r0 + ks * 32 + 4);
        float4 b0 = *(const float4*)(r1 + ks * 32), b1 = *(const float4*)(r1 + ks * 32 + 4);
        float4 c0 = *(const float4*)(r2 + ks * 32), c1 = *(const float4*)(r2 + ks * 32 + 4);
        v[ks][0] = a0.x + b0.x + c0.x; v[ks][1] = a0.y + b0.y + c0.y;
        v[ks][2] = a0.z + b0.z + c0.z; v[ks][3] = a0.w + b0.w + c0.w;
        v[ks][4] = a1.x + b1.x + c1.x; v[ks][5] = a1.y + b1.y + c1.y;
        v[ks][6] = a1.z + b1.z + c1.z; v[ks][7] = a1.w + b1.w + c1.w;
    }
}

__device__ __forceinline__ void loadrow(const float* __restrict__ rp, float (&v)[4][8]) {
    #pragma unroll
    for (int ks = 0; ks < 4; ks++) {
        float4 a = *(const float4*)(rp + ks * 32), b = *(const float4*)(rp + ks * 32 + 4);
        v[ks][0] = a.x; v[ks][1] = a.y; v[ks][2] = a.z; v[ks][3] = a.w;
        v[ks][4] = b.x; v[ks][5] = b.y; v[ks][6] = b.z; v[ks][7] = b.w;
    }
}

__device__ __forceinline__ void gatherCSR(const int* __restrict__ offs,
                                          const int* __restrict__ csr,
                                          const float* __restrict__ xcn,
                                          const float* __restrict__ norms,
                                          int arow, int g, float (&v)[4][8]) {
    #pragma unroll
    for (int ks = 0; ks < 4; ks++)
        #pragma unroll
        for (int j = 0; j < 8; j++) v[ks][j] = 0.f;
    const int s = offs[arow], e = offs[arow + 1];
    for (int p = s; p < e; p++) {
        const int c = csr[p];
        const float sc = norms[c];
        const float* q = xcn + (size_t)c * D + g * 8;
        #pragma unroll
        for (int ks = 0; ks < 4; ks++) {
            float4 a = *(const float4*)(q + ks * 32), b = *(const float4*)(q + ks * 32 + 4);
            v[ks][0] = fmaf(sc, a.x, v[ks][0]); v[ks][1] = fmaf(sc, a.y, v[ks][1]);
            v[ks][2] = fmaf(sc, a.z, v[ks][2]); v[ks][3] = fmaf(sc, a.w, v[ks][3]);
            v[ks][4] = fmaf(sc, b.x, v[ks][4]); v[ks][5] = fmaf(sc, b.y, v[ks][5]);
            v[ks][6] = fmaf(sc, b.z, v[ks][6]); v[ks][7] = fmaf(sc, b.w, v[ks][7]);
        }
    }
}

// ---------------- LC phase: 256 clause rows per block ------------------------
__device__ __forceinline__ void lc_phase(
    int blk, int tid, const int* __restrict__ edge_lit, const float* __restrict__ xl,
    const float* __restrict__ xc_prev, const unsigned short* __restrict__ pk,
    const float* __restrict__ bih, const float* __restrict__ bhh,
    float* __restrict__ xc_norm, float* __restrict__ norms, unsigned short* lds) {
    const int wid = tid >> 6, lane = tid & 63;
    const int m = lane & 15, g = lane >> 4;
    const int rowbase = blk * 256;
    const int arow0 = rowbase + wid * 32 + m, arow1 = arow0 + 16;

    // stage ih_lc + hh_lc (hi/lo, 128 KB contiguous in pk)
    {
        const short8v* src = (const short8v*)pk;
        short8v* dst = (short8v*)lds;
        #pragma unroll
        for (int i = 0; i < 16; i++) dst[i * 512 + tid] = src[i * 512 + tid];
    }
    float v0[4][8], v1[4][8];
    gather3(edge_lit, xl, arow0, g, v0);
    gather3(edge_lit, xl, arow1, g, v1);
    __syncthreads();

    short8v a0h[4], a0l[4], a1h[4], a1l[4];
    #pragma unroll
    for (int ks = 0; ks < 4; ks++) { cvt_frag(v0[ks], a0h[ks], a0l[ks]); cvt_frag(v1[ks], a1h[ks], a1l[ks]); }

    f32x4 acc0[8], acc1[8];
    #pragma unroll
    for (int n = 0; n < 8; n++) { acc0[n] = (f32x4)0.f; acc1[n] = (f32x4)0.f; }

    float vh0[4][8], vh1[4][8];
    loadrow(xc_prev + (size_t)arow0 * D + g * 8, vh0);
    loadrow(xc_prev + (size_t)arow1 * D + g * 8, vh1);

    #pragma unroll
    for (int ks = 0; ks < 4; ks++)
        #pragma unroll
        for (int n = 0; n < 8; n++)
            mm3l(acc0[n], acc1[n], a0h[ks], a0l[ks], a1h[ks], a1l[ks],
                 lds, ((n * 4 + ks) * 64 + lane) * 8);

    #pragma unroll
    for (int ks = 0; ks < 4; ks++) { cvt_frag(vh0[ks], a0h[ks], a0l[ks]); cvt_frag(vh1[ks], a1h[ks], a1l[ks]); }
    #pragma unroll
    for (int ks = 0; ks < 4; ks++)
        #pragma unroll
        for (int n = 0; n < 8; n++)
            mm3l(acc0[n], acc1[n], a0h[ks], a0l[ks], a1h[ks], a1l[ks],
                 lds + 2 * PKM, ((n * 4 + ks) * 64 + lane) * 8);

    float bias[8];
    #pragma unroll
    for (int n = 0; n < 8; n++) bias[n] = bih[n * 16 + m] + bhh[n * 16 + m];

    #pragma unroll
    for (int rg = 0; rg < 2; rg++) {
        const int obase = rowbase + wid * 32 + rg * 16 + g * 4;
        #pragma unroll
        for (int r = 0; r < 4; r++) {
            float w[8], ss = 0.f;
            #pragma unroll
            for (int n = 0; n < 8; n++) {
                float a = rg ? acc1[n][r] : acc0[n][r];
                w[n] = ftanh(a + bias[n]); ss += w[n] * w[n];
            }
            ss += __shfl_xor(ss, 1); ss += __shfl_xor(ss, 2);
            ss += __shfl_xor(ss, 4); ss += __shfl_xor(ss, 8);
            const float rn = __builtin_amdgcn_rsqf(ss);
            const size_t rowoff = (size_t)(obase + r) * D + m;
            #pragma unroll
            for (int n = 0; n < 8; n++) xc_norm[rowoff + n * 16] = w[n] * rn;
            if (m == 0) norms[obase + r] = ss * rn;   // ||row||
        }
    }
}

// ---------------- CL phase: 128 literal rows per block, degree-sorted --------
__device__ __forceinline__ void cl_phase(
    int blk, int tid,
    const int* __restrict__ offs, const int* __restrict__ csr,
    const int* __restrict__ perm,
    const float* __restrict__ xc_norm, const float* __restrict__ norms,
    const float* __restrict__ xl, const unsigned short* __restrict__ pk,
    const float* __restrict__ bih, const float* __restrict__ bhh,
    const float* __restrict__ tv, const float* __restrict__ vw,
    const float* __restrict__ vb,
    float* __restrict__ xl_out, float* __restrict__ truth,
    float* __restrict__ truth2, float* __restrict__ vote, unsigned short* lds) {
    float* scr = (float*)(lds + 4 * PKM);
    float* ssx = scr; float* twx = scr + 256; float* vwx = scr + 512;
    const int wid = tid >> 6, lane = tid & 63;
    const int m = lane & 15, g = lane >> 4;
    const int rg = wid >> 1, nh = wid & 1, nbase = nh * 4;
    const int lbase = blk * 128;
    const int arow0 = lbase + perm[lbase + rg * 32 + m];
    const int arow1 = lbase + perm[lbase + rg * 32 + 16 + m];

    // stage bufA=ih_msg (mat3), bufB=hh (mat2)
    {
        const short8v* srcA = (const short8v*)(pk + 3 * 2 * PKM);
        const short8v* srcB = (const short8v*)(pk + 2 * 2 * PKM);
        short8v* dA = (short8v*)lds;
        short8v* dB = (short8v*)(lds + 2 * PKM);
        #pragma unroll
        for (int i = 0; i < 8; i++) dA[i * 512 + tid] = srcA[i * 512 + tid];
        #pragma unroll
        for (int i = 0; i < 8; i++) dB[i * 512 + tid] = srcB[i * 512 + tid];
    }
    float v0[4][8], v1[4][8];
    gatherCSR(offs, csr, xc_norm, norms, arow0, g, v0);
    gatherCSR(offs, csr, xc_norm, norms, arow1, g, v1);
    __syncthreads();                                   // b1

    short8v a0h[4], a0l[4], a1h[4], a1l[4];
    #pragma unroll
    for (int ks = 0; ks < 4; ks++) { cvt_frag(v0[ks], a0h[ks], a0l[ks]); cvt_frag(v1[ks], a1h[ks], a1l[ks]); }

    f32x4 acc0[4], acc1[4];
    #pragma unroll
    for (int n = 0; n < 4; n++) { acc0[n] = (f32x4)0.f; acc1[n] = (f32x4)0.f; }

    // T14 split: issue flip-restage + hidden loads before msg MFMAs
    short8v fr[8];
    {
        const short8v* srcF = (const short8v*)(pk + 4 * 2 * PKM);  // ih_flip
        #pragma unroll
        for (int i = 0; i < 8; i++) fr[i] = srcF[i * 512 + tid];
    }
    float vh0[4][8], vh1[4][8];
    loadrow(xl + (size_t)arow0 * D + g * 8, vh0);
    loadrow(xl + (size_t)arow1 * D + g * 8, vh1);

    #pragma unroll
    for (int ks = 0; ks < 4; ks++)
        #pragma unroll
        for (int nn = 0; nn < 4; nn++)
            mm3l(acc0[nn], acc1[nn], a0h[ks], a0l[ks], a1h[ks], a1l[ks],
                 lds, (((nbase + nn) * 4 + ks) * 64 + lane) * 8);

    __syncthreads();                                   // b2
    {
        short8v* dA = (short8v*)lds;
        #pragma unroll
        for (int i = 0; i < 8; i++) dA[i * 512 + tid] = fr[i];
    }
    #pragma unroll
    for (int ks = 0; ks < 4; ks++) { cvt_frag(vh0[ks], a0h[ks], a0l[ks]); cvt_frag(vh1[ks], a1h[ks], a1l[ks]); }

    float vf0[4][8], vf1[4][8];
    loadrow(xl + (size_t)(arow0 ^ 256) * D + g * 8, vf0);
    loadrow(xl + (size_t)(arow1 ^ 256) * D + g * 8, vf1);

    #pragma unroll
    for (int ks = 0; ks < 4; ks++)
        #pragma unroll
        for (int nn = 0; nn < 4; nn++)
            mm3l(acc0[nn], acc1[nn], a0h[ks], a0l[ks], a1h[ks], a1l[ks],
                 lds + 2 * PKM, (((nbase + nn) * 4 + ks) * 64 + lane) * 8);

    __syncthreads();                                   // b3
    #pragma unroll
    for (int ks = 0; ks < 4; ks++) { cvt_frag(vf0[ks], a0h[ks], a0l[ks]); cvt_frag(vf1[ks], a1h[ks], a1l[ks]); }
    #pragma unroll
    for (int ks = 0; ks < 4; ks++)
        #pragma unroll
        for (int nn = 0; nn < 4; nn++)
            mm3l(acc0[nn], acc1[nn], a0h[ks], a0l[ks], a1h[ks], a1l[ks],
                 lds, (((nbase + nn) * 4 + ks) * 64 + lane) * 8);

    float bias[4], tvv[4], vwv[4];
    #pragma unroll
    for (int nn = 0; nn < 4; nn++) {
        int n = nbase + nn;
        bias[nn] = bih[n * 16 + m] + bhh[n * 16 + m];
        tvv[nn] = tv[n * 16 + m];
        vwv[nn] = vote ? vw[n * 16 + m] : 0.f;
    }
    float wv[2][4][4];
    #pragma unroll
    for (int rgi = 0; rgi < 2; rgi++) {
        #pragma unroll
        for (int r = 0; r < 4; r++) {
            float ssp = 0.f, twp = 0.f, vwp = 0.f;
            #pragma unroll
            for (int nn = 0; nn < 4; nn++) {
                float a = rgi ? acc1[nn][r] : acc0[nn][r];
                float w = ftanh(a + bias[nn]);
                wv[rgi][r][nn] = w;
                ssp += w * w; twp += w * tvv[nn]; vwp += w * vwv[nn];
            }
            ssp += __shfl_xor(ssp, 1); ssp += __shfl_xor(ssp, 2);
            ssp += __shfl_xor(ssp, 4); ssp += __shfl_xor(ssp, 8);
            twp += __shfl_xor(twp, 1); twp += __shfl_xor(twp, 2);
            twp += __shfl_xor(twp, 4); twp += __shfl_xor(twp, 8);
            if (vote) {
                vwp += __shfl_xor(vwp, 1); vwp += __shfl_xor(vwp, 2);
                vwp += __shfl_xor(vwp, 4); vwp += __shfl_xor(vwp, 8);
            }
            if (m == 0) {
                int rl = rg * 32 + rgi * 16 + g * 4 + r;
                ssx[rl * 2 + nh] = ssp;
                twx[rl * 2 + nh] = twp;
                if (vote) vwx[rl * 2 + nh] = vwp;
            }
        }
    }
    __syncthreads();                                   // b4
    const float vb0 = vote ? vb[0] : 0.f;
    #pragma unroll
    for (int rgi = 0; rgi < 2; rgi++) {
        #pragma unroll
        for (int r = 0; r < 4; r++) {
            const int rl = rg * 32 + rgi * 16 + g * 4 + r;
            const int grow = lbase + perm[lbase + rl];
            const float ss = ssx[rl * 2] + ssx[rl * 2 + 1];
            const float rn = __builtin_amdgcn_rsqf(ss);
            const size_t rowoff = (size_t)grow * D + m;
            #pragma unroll
            for (int nn = 0; nn < 4; nn++)
                xl_out[rowoff + (nbase + nn) * 16] = wv[rgi][r][nn] * rn;
            if (m == 0 && nh == 0) {
                const float td = rn * (twx[rl * 2] + twx[rl * 2 + 1]);
                truth[grow] = td;
                if (truth2) truth2[grow] = td;
                if (vote) vote[grow] = rn * (vwx[rl * 2] + vwx[rl * 2 + 1]) + vb0;
            }
        }
    }
}

// ---------------- the persistent fused kernel --------------------------------
__global__ __launch_bounds__(512, 2) void fused(
    const int* __restrict__ edge_lit,
    const int* __restrict__ offs, const int* __restrict__ csr,
    const int* __restrict__ perm,
    const float* __restrict__ x_l0, const float* __restrict__ x_c0,
    const unsigned short* __restrict__ pk,
    const float* __restrict__ b_ih_lc, const float* __restrict__ b_hh_lc,
    const float* __restrict__ b_ih_cl, const float* __restrict__ b_hh_cl,
    const float* __restrict__ tv, const float* __restrict__ vw,
    const float* __restrict__ vb,
    float* __restrict__ out, float* __restrict__ xl_ws,
    float* __restrict__ norms, int* __restrict__ bar) {
    extern __shared__ __align__(16) unsigned short lds[];
    const int p = blockIdx.x;
    const int blk = (p & 7) * 32 + (p >> 3);   // XCD-chunked: graph's 4 blocks share XCD
    const int graph = blk >> 2;
    int* gctr = bar + graph;
    const int tid = threadIdx.x, wid = tid >> 6, lane = tid & 63;

    float* xl_o  = out + OFF_XL;
    float* call  = out + OFF_CALL;
    float* tall  = out + OFF_TALL;
    int ph = 0;

    // ---- init: normalize x_l0 (+truth0), x_c0 (own rows only) ----
    for (int r = wid; r < 128; r += 8) {
        const int row = blk * 128 + r;
        const float* src = x_l0 + (size_t)row * D;
        float a = src[lane], b = src[lane + 64];
        float ss = a * a + b * b;
        #pragma unroll
        for (int k = 32; k; k >>= 1) ss += __shfl_xor(ss, k);
        const float rn = __builtin_amdgcn_rsqf(ss);
        const float ya = a * rn, yb = b * rn;
        float* o = xl_o + (size_t)row * D;
        o[lane] = ya; o[lane + 64] = yb;
        float dv = ya * tv[lane] + yb * tv[lane + 64];
        #pragma unroll
        for (int k = 32; k; k >>= 1) dv += __shfl_xor(dv, k);
        if (lane == 0) { tall[row] = dv; out[OFF_T0 + row] = dv; }
    }
    for (int r = wid; r < 256; r += 8) {
        const int row = blk * 256 + r;
        const float* src = x_c0 + (size_t)row * D;
        float a = src[lane], b = src[lane + 64];
        float ss = a * a + b * b;
        #pragma unroll
        for (int k = 32; k; k >>= 1) ss += __shfl_xor(ss, k);
        const float rn = __builtin_amdgcn_rsqf(ss);
        float* o = call + (size_t)row * D;
        o[lane] = a * rn; o[lane + 64] = b * rn;
    }
    gbar(gctr, 4 * ++ph);

    for (int t = 1; t <= T; t++) {
        const float* xls = (t & 1) ? xl_o : xl_ws;
        float*       xld = (t & 1) ? xl_ws : xl_o;
        lc_phase(blk, tid, edge_lit, xls, call + (size_t)(t - 1) * NC * D, pk,
                 b_ih_lc, b_hh_lc, call + (size_t)t * NC * D, norms, lds);
        gbar(gctr, 4 * ++ph);
        cl_phase(blk, tid, offs, csr, perm,
                 call + (size_t)t * NC * D, norms, xls, pk,
                 b_ih_cl, b_hh_cl, tv, vw, vb,
                 xld, tall + (size_t)t * NL,
                 (t == T) ? out + OFF_TLAST : nullptr,
                 (t == T) ? out + OFF_VOTE : nullptr, lds);
        if (t < T) gbar(gctr, 4 * ++ph);
    }
}

// ---------------- mean-pool --------------------------------------------------
__global__ void pool_kernel(const float* __restrict__ votes, float* __restrict__ pool) {
    __shared__ float s[4];
    int g = blockIdx.x, t = threadIdx.x;
    float v = votes[g * LITS_PER + t] + votes[g * LITS_PER + 256 + t];
    #pragma unroll
    for (int m = 32; m; m >>= 1) v += __shfl_xor(v, m);
    if ((t & 63) == 0) s[t >> 6] = v;
    __syncthreads();
    if (t == 0) pool[g] = (s[0] + s[1] + s[2] + s[3]) * (1.0f / LITS_PER);
}

// ---------------- launch ----------------------------------------------------
extern "C" void kernel_launch(void* const* d_in, const int* in_sizes, int n_in,
                              void* d_out, int out_size, void* d_ws, size_t ws_size,
                              hipStream_t stream) {
    const int*   edge_lit = (const int*)d_in[1];
    const float* x_l0     = (const float*)d_in[2];
    const float* x_c0     = (const float*)d_in[3];
    const float* W_ih_lc  = (const float*)d_in[4];
    const float* W_hh_lc  = (const float*)d_in[5];
    const float* b_ih_lc  = (const float*)d_in[6];
    const float* b_hh_lc  = (const float*)d_in[7];
    const float* W_ih_cl  = (const float*)d_in[8];
    const float* W_hh_cl  = (const float*)d_in[9];
    const float* b_ih_cl  = (const float*)d_in[10];
    const float* b_hh_cl  = (const float*)d_in[11];
    const float* L_vote_w = (const float*)d_in[12];
    const float* L_vote_b = (const float*)d_in[13];
    const float* true_vec = (const float*)d_in[14];
    // d_in[15] = num_iters (=8, compile-time T)

    float* out = (float*)d_out;

    // workspace
    float* norms  = (float*)d_ws;                                   // NC
    float* xl_ws  = norms + NC;                                     // NL*D
    unsigned short* pk = (unsigned short*)(xl_ws + (size_t)NL * D); // PK_TOT
    int* counts = (int*)(pk + PK_TOT);                              // NL
    int* offs   = counts + NL;                                      // NL+1
    int* cursor = offs + NL + 1;                                    // NL
    int* csr    = cursor + NL;                                      // NE
    int* perm   = csr + NE;                                         // NL
    int* bar    = perm + NL;                                        // Bg

    hipMemsetAsync(counts, 0, NL * sizeof(int), stream);
    hipMemsetAsync(bar, 0, Bg * sizeof(int), stream);

    pack5<<<5 * PKM / 256, 256, 0, stream>>>(W_ih_lc, W_hh_lc, W_hh_cl, W_ih_cl, pk);
    csr_count<<<NE / 256, 256, 0, stream>>>(edge_lit, counts);
    csr_scan<<<1, 1024, 0, stream>>>(counts, offs, cursor);
    csr_fill<<<NE / 256, 256, 0, stream>>>(edge_lit, cursor, csr);
    csr_sort<<<NL / 256, 256, 0, stream>>>(offs, csr);
    make_perm<<<NL / 128, 128, 0, stream>>>(counts, perm);

    fused<<<256, 512, SHM, stream>>>(
        edge_lit, offs, csr, perm, x_l0, x_c0, pk,
        b_ih_lc, b_hh_lc, b_ih_cl, b_hh_cl,
        true_vec, L_vote_w, L_vote_b,
        out, xl_ws, norms, bar);

    pool_kernel<<<Bg, 256, 0, stream>>>(out + OFF_VOTE, out + OFF_POOL);
}

// Round 8
// 670.244 us; speedup vs baseline: 2.2769x; 2.2769x over previous
//
#include <hip/hip_runtime.h>
#include <math.h>

// NeuroSAT RNN forward on MI355X — multi-kernel, MFMA bf16x2 (A-split, B single
// bf16 plane), 2 blocks/CU (16 waves/CU), weights LDS-staged.
namespace {
constexpr int NVARS    = 256;
constexpr int LITS_PER = 2 * NVARS;     // 512
constexpr int Bg       = 64;            // graphs
constexpr int NL       = Bg * LITS_PER; // 32768 literals
constexpr int CLS_PER  = 1024;
constexpr int NC       = Bg * CLS_PER;  // 65536 clauses
constexpr int NE       = NC * 3;        // 196608 edges (K=3)
constexpr int D        = 128;
constexpr int T        = 8;             // num_iters (fixed scalar input)

// d_out flat layout (reference tuple order)
constexpr size_t OFF_VOTE  = 0;                                  // [NL]
constexpr size_t OFF_XL    = (size_t)NL;                         // [NL*D]   (x_l state)
constexpr size_t OFF_POOL  = OFF_XL + (size_t)NL * D;            // [Bg]
constexpr size_t OFF_TLAST = OFF_POOL + Bg;                      // [NL]
constexpr size_t OFF_TALL  = OFF_TLAST + NL;                     // [(T+1)*NL]
constexpr size_t OFF_CALL  = OFF_TALL + (size_t)(T + 1) * NL;    // [(T+1)*NC*D] (x_c state)
constexpr size_t OFF_T0    = OFF_CALL + (size_t)(T + 1) * NC * D;// [NL]

// packed weights, single bf16 plane per matrix, frag order [n][ks][lane][8]:
// 0: W_ih_lc | 1: W_hh_lc | 2: W_hh_cl | 3: W_ih_cl[:, :128] | 4: W_ih_cl[:, 128:]
constexpr int PKM    = 16384;           // ushorts per matrix
constexpr int PK_TOT = 5 * PKM;         // 81920
constexpr size_t SHM_LC = 2 * PKM * sizeof(unsigned short);          // 64 KB
constexpr size_t SHM_CL = 2 * PKM * sizeof(unsigned short) + 1536;   // 64 KB + scratch
} // namespace

typedef __attribute__((ext_vector_type(8))) short short8v;
typedef __attribute__((ext_vector_type(4))) float f32x4;

__device__ __forceinline__ unsigned short f2bf(float v) {
    unsigned u = __float_as_uint(v);
    return (unsigned short)((u + 0x7fffu + ((u >> 16) & 1u)) >> 16);  // RNE
}
__device__ __forceinline__ float bf2f(unsigned short b) {
    return __uint_as_float(((unsigned)b) << 16);
}
__device__ __forceinline__ void cvt_frag(const float (&v)[8], short8v& ah, short8v& al) {
    #pragma unroll
    for (int j = 0; j < 8; j++) {
        unsigned short h = f2bf(v[j]);
        ah[j] = (short)h;
        al[j] = (short)f2bf(v[j] - bf2f(h));
    }
}
__device__ __forceinline__ float ftanh(float x) {
    float e = __builtin_amdgcn_exp2f(x * 2.885390081777926814f);
    return 1.0f - 2.0f * __builtin_amdgcn_rcpf(e + 1.0f);
}
// bf16x2: A split (ah+al), B single bf16 plane from LDS. 2 MFMAs, 1 LDS read.
__device__ __forceinline__ void mm2(f32x4& c, short8v ah, short8v al,
                                    const unsigned short* buf, int off) {
    short8v b = *(const short8v*)(buf + off);
    c = __builtin_amdgcn_mfma_f32_16x16x32_bf16(ah, b, c, 0, 0, 0);
    c = __builtin_amdgcn_mfma_f32_16x16x32_bf16(al, b, c, 0, 0, 0);
}

// ---------------- W packing (single plane) -----------------------------------
__global__ __launch_bounds__(256) void pack5(
    const float* __restrict__ ihlc, const float* __restrict__ hhlc,
    const float* __restrict__ hhcl, const float* __restrict__ ihcl,
    unsigned short* __restrict__ pk) {
    int idx = blockIdx.x * 256 + threadIdx.x;
    int mat = idx >> 14, rel = idx & 16383;
    int j = rel & 7, lane = (rel >> 3) & 63, ks = (rel >> 9) & 3, n = rel >> 11;
    int r = n * 16 + (lane & 15);
    int k = ks * 32 + (lane >> 4) * 8 + j;
    float w;
    if (mat == 0)      w = ihlc[r * 128 + k];
    else if (mat == 1) w = hhlc[r * 128 + k];
    else if (mat == 2) w = hhcl[r * 128 + k];
    else if (mat == 3) w = ihcl[r * 256 + k];
    else               w = ihcl[r * 256 + 128 + k];
    pk[mat * PKM + rel] = f2bf(w);
}

// ---------------- CSR build --------------------------------------------------
__global__ void csr_count(const int* __restrict__ edge_lit, int* __restrict__ counts) {
    int e = blockIdx.x * blockDim.x + threadIdx.x;
    if (e < NE) atomicAdd(&counts[edge_lit[e]], 1);
}

__global__ __launch_bounds__(1024) void csr_scan(const int* __restrict__ counts,
                                                 int* __restrict__ offs,
                                                 int* __restrict__ cursor) {
    __shared__ int part[1024];
    const int t = threadIdx.x;
    const int base = t * 32;
    int local[32];
    int s = 0;
    for (int i = 0; i < 32; i++) { local[i] = s; s += counts[base + i]; }
    part[t] = s;
    __syncthreads();
    for (int d = 1; d < 1024; d <<= 1) {
        int v = 0;
        if (t >= d) v = part[t - d];
        __syncthreads();
        if (t >= d) part[t] += v;
        __syncthreads();
    }
    const int excl = (t == 0) ? 0 : part[t - 1];
    for (int i = 0; i < 32; i++) {
        int o = excl + local[i];
        offs[base + i] = o;
        cursor[base + i] = o;
    }
    if (t == 1023) offs[NL] = part[1023];
}

__global__ void csr_fill(const int* __restrict__ edge_lit, int* __restrict__ cursor,
                         int* __restrict__ csr) {
    int e = blockIdx.x * blockDim.x + threadIdx.x;
    if (e < NE) {
        int l = edge_lit[e];
        int p = atomicAdd(&cursor[l], 1);
        csr[p] = e / 3;
    }
}

__global__ void csr_sort(const int* __restrict__ offs, int* __restrict__ csr) {
    int l = blockIdx.x * blockDim.x + threadIdx.x;
    if (l >= NL) return;
    int s = offs[l], e = offs[l + 1];
    for (int i = s + 1; i < e; i++) {
        int v = csr[i];
        int j = i - 1;
        while (j >= s && csr[j] > v) { csr[j + 1] = csr[j]; j--; }
        csr[j + 1] = v;
    }
}

// per-64-literal-group degree sort (stable) -> perm of local indices
__global__ __launch_bounds__(64) void make_perm(const int* __restrict__ counts,
                                                int* __restrict__ perm) {
    __shared__ int d[64];
    const int b = blockIdx.x, i = threadIdx.x;
    d[i] = counts[b * 64 + i];
    __syncthreads();
    const int di = d[i];
    int rank = 0;
    for (int j = 0; j < 64; j++) {
        int dj = d[j];
        rank += (dj < di) || (dj == di && j < i);
    }
    perm[b * 64 + rank] = i;
}

// ---------------- init: row L2-normalize (+ fused dot) -----------------------
__global__ void rownorm_dot(const float* __restrict__ in, float* __restrict__ out,
                            const float* __restrict__ dotw, float* __restrict__ dot0,
                            float* __restrict__ dot1, int nrows) {
    int wave = (int)((blockIdx.x * blockDim.x + threadIdx.x) >> 6);
    int lane = threadIdx.x & 63;
    if (wave >= nrows) return;
    const float* r = in + (size_t)wave * D;
    float v0 = r[lane], v1 = r[lane + 64];
    float ss = v0 * v0 + v1 * v1;
    #pragma unroll
    for (int m = 32; m; m >>= 1) ss += __shfl_xor(ss, m);
    float rn = 1.0f / sqrtf(ss);
    float y0 = v0 * rn, y1 = v1 * rn;
    float* o = out + (size_t)wave * D;
    o[lane] = y0;
    o[lane + 64] = y1;
    if (dotw) {
        float dv = y0 * dotw[lane] + y1 * dotw[lane + 64];
        #pragma unroll
        for (int m = 32; m; m >>= 1) dv += __shfl_xor(dv, m);
        if (lane == 0) {
            dot0[wave] = dv;
            if (dot1) dot1[wave] = dv;
        }
    }
}

// -------- gather helpers -----------------------------------------------------
__device__ __forceinline__ void gather3(const int* __restrict__ ep,
                                        const float* __restrict__ xl, int arow, int g,
                                        float (&v)[4][8]) {
    int e0 = ep[3 * arow], e1 = ep[3 * arow + 1], e2 = ep[3 * arow + 2];
    const float* r0 = xl + (size_t)e0 * D + g * 8;
    const float* r1 = xl + (size_t)e1 * D + g * 8;
    const float* r2 = xl + (size_t)e2 * D + g * 8;
    #pragma unroll
    for (int ks = 0; ks < 4; ks++) {
        float4 a0 = *(const float4*)(r0 + ks * 32), a1 = *(const float4*)(r0 + ks * 32 + 4);
        float4 b0 = *(const float4*)(r1 + ks * 32), b1 = *(const float4*)(r1 + ks * 32 + 4);
        float4 c0 = *(const float4*)(r2 + ks * 32), c1 = *(const float4*)(r2 + ks * 32 + 4);
        v[ks][0] = a0.x + b0.x + c0.x; v[ks][1] = a0.y + b0.y + c0.y;
        v[ks][2] = a0.z + b0.z + c0.z; v[ks][3] = a0.w + b0.w + c0.w;
        v[ks][4] = a1.x + b1.x + c1.x; v[ks][5] = a1.y + b1.y + c1.y;
        v[ks][6] = a1.z + b1.z + c1.z; v[ks][7] = a1.w + b1.w + c1.w;
    }
}

__device__ __forceinline__ void loadrow(const float* __restrict__ rp, float (&v)[4][8]) {
    #pragma unroll
    for (int ks = 0; ks < 4; ks++) {
        float4 a = *(const float4*)(rp + ks * 32), b = *(const float4*)(rp + ks * 32 + 4);
        v[ks][0] = a.x; v[ks][1] = a.y; v[ks][2] = a.z; v[ks][3] = a.w;
        v[ks][4] = b.x; v[ks][5] = b.y; v[ks][6] = b.z; v[ks][7] = b.w;
    }
}

__device__ __forceinline__ void gatherCSR(const int* __restrict__ offs,
                                          const int* __restrict__ csr,
                                          const float* __restrict__ xcn,
                                          const float* __restrict__ norms,
                                          int arow, int g, float (&v)[4][8]) {
    #pragma unroll
    for (int ks = 0; ks < 4; ks++)
        #pragma unroll
        for (int j = 0; j < 8; j++) v[ks][j] = 0.f;
    const int s = offs[arow], e = offs[arow + 1];
    for (int p = s; p < e; p++) {
        const int c = csr[p];
        const float sc = norms[c];
        const float* q = xcn + (size_t)c * D + g * 8;
        #pragma unroll
        for (int ks = 0; ks < 4; ks++) {
            float4 a = *(const float4*)(q + ks * 32), b = *(const float4*)(q + ks * 32 + 4);
            v[ks][0] = fmaf(sc, a.x, v[ks][0]); v[ks][1] = fmaf(sc, a.y, v[ks][1]);
            v[ks][2] = fmaf(sc, a.z, v[ks][2]); v[ks][3] = fmaf(sc, a.w, v[ks][3]);
            v[ks][4] = fmaf(sc, b.x, v[ks][4]); v[ks][5] = fmaf(sc, b.y, v[ks][5]);
            v[ks][6] = fmaf(sc, b.z, v[ks][6]); v[ks][7] = fmaf(sc, b.w, v[ks][7]);
        }
    }
}

// ---------------- LC: 512 blocks x 512 thr; 128 rows/block; wave=16 rows -----
__global__ __launch_bounds__(512, 4) void lc_mfma(
    const int* __restrict__ edge_lit, const float* __restrict__ xl,
    const float* __restrict__ xc_prev, const unsigned short* __restrict__ pk,
    const float* __restrict__ bih, const float* __restrict__ bhh,
    float* __restrict__ xc_norm, float* __restrict__ norms) {
    extern __shared__ __align__(16) unsigned short lds[];  // [0,PKM)=ih, [PKM,2PKM)=hh
    const int tid = threadIdx.x, wid = tid >> 6, lane = tid & 63;
    const int m = lane & 15, g = lane >> 4;
    const int p = blockIdx.x;
    const int blk = (p & 7) * 64 + (p >> 3);    // XCD-chunked, grid=512 bijective
    const int rowbase = blk * 128;
    const int arow = rowbase + wid * 16 + m;

    // stage ih_lc + hh_lc (64 KB contiguous in pk)
    {
        const short8v* src = (const short8v*)pk;
        short8v* dst = (short8v*)lds;
        #pragma unroll
        for (int i = 0; i < 8; i++) dst[i * 512 + tid] = src[i * 512 + tid];
    }
    float v[4][8];
    gather3(edge_lit, xl, arow, g, v);
    float vh[4][8];
    loadrow(xc_prev + (size_t)arow * D + g * 8, vh);
    __syncthreads();

    short8v ah[4], al[4];
    #pragma unroll
    for (int ks = 0; ks < 4; ks++) cvt_frag(v[ks], ah[ks], al[ks]);

    f32x4 acc[8];
    #pragma unroll
    for (int n = 0; n < 8; n++) acc[n] = (f32x4)0.f;

    #pragma unroll
    for (int ks = 0; ks < 4; ks++)
        #pragma unroll
        for (int n = 0; n < 8; n++)
            mm2(acc[n], ah[ks], al[ks], lds, ((n * 4 + ks) * 64 + lane) * 8);

    #pragma unroll
    for (int ks = 0; ks < 4; ks++) cvt_frag(vh[ks], ah[ks], al[ks]);
    #pragma unroll
    for (int ks = 0; ks < 4; ks++)
        #pragma unroll
        for (int n = 0; n < 8; n++)
            mm2(acc[n], ah[ks], al[ks], lds + PKM, ((n * 4 + ks) * 64 + lane) * 8);

    float bias[8];
    #pragma unroll
    for (int n = 0; n < 8; n++) bias[n] = bih[n * 16 + m] + bhh[n * 16 + m];

    const int obase = rowbase + wid * 16 + g * 4;
    #pragma unroll
    for (int r = 0; r < 4; r++) {
        float w[8], ss = 0.f;
        #pragma unroll
        for (int n = 0; n < 8; n++) { w[n] = ftanh(acc[n][r] + bias[n]); ss += w[n] * w[n]; }
        ss += __shfl_xor(ss, 1); ss += __shfl_xor(ss, 2);
        ss += __shfl_xor(ss, 4); ss += __shfl_xor(ss, 8);
        const float rn = __builtin_amdgcn_rsqf(ss);
        const size_t rowoff = (size_t)(obase + r) * D + m;
        #pragma unroll
        for (int n = 0; n < 8; n++) xc_norm[rowoff + n * 16] = w[n] * rn;
        if (m == 0) norms[obase + r] = ss * rn;   // ||row||
    }
}

// ------- CL: 512 blocks x 512 thr; 64 rows/block; wave=16 rows x N-half ------
__global__ __launch_bounds__(512, 4) void cl_mfma(
    const int* __restrict__ offs, const int* __restrict__ csr,
    const int* __restrict__ perm,
    const float* __restrict__ xc_norm, const float* __restrict__ norms,
    const float* __restrict__ xl, const unsigned short* __restrict__ pk,
    const float* __restrict__ bih, const float* __restrict__ bhh,
    const float* __restrict__ tv, const float* __restrict__ vw,
    const float* __restrict__ vb,
    float* __restrict__ xl_out, float* __restrict__ truth,
    float* __restrict__ truth2, float* __restrict__ vote) {
    extern __shared__ __align__(16) unsigned short lds[];
    // buf0 [0,PKM): ih_msg -> later ih_flip ; buf1 [PKM,2PKM): hh
    float* scr = (float*)(lds + 2 * PKM);
    float* ssx = scr; float* twx = scr + 128; float* vwx = scr + 256;

    const int tid = threadIdx.x, wid = tid >> 6, lane = tid & 63;
    const int m = lane & 15, g = lane >> 4;
    const int rw = wid >> 1, nh = wid & 1, nbase = nh * 4;
    const int p0 = blockIdx.x;
    const int blk = (p0 & 7) * 64 + (p0 >> 3);
    const int lbase = blk * 64;
    const int arow = lbase + perm[lbase + rw * 16 + m];

    // stage buf0=ih_msg (mat3), buf1=hh (mat2)
    {
        const short8v* srcA = (const short8v*)(pk + 3 * PKM);
        const short8v* srcB = (const short8v*)(pk + 2 * PKM);
        short8v* d0 = (short8v*)lds;
        short8v* d1 = (short8v*)(lds + PKM);
        #pragma unroll
        for (int i = 0; i < 4; i++) d0[i * 512 + tid] = srcA[i * 512 + tid];
        #pragma unroll
        for (int i = 0; i < 4; i++) d1[i * 512 + tid] = srcB[i * 512 + tid];
    }
    float v[4][8];
    gatherCSR(offs, csr, xc_norm, norms, arow, g, v);
    __syncthreads();                                   // b1

    short8v ah[4], al[4];
    #pragma unroll
    for (int ks = 0; ks < 4; ks++) cvt_frag(v[ks], ah[ks], al[ks]);

    f32x4 acc[4];
    #pragma unroll
    for (int n = 0; n < 4; n++) acc[n] = (f32x4)0.f;

    // T14 split: issue flip-W prefetch + hidden-row loads before msg MFMAs
    short8v fr[4];
    {
        const short8v* srcF = (const short8v*)(pk + 4 * PKM);  // ih_flip
        #pragma unroll
        for (int i = 0; i < 4; i++) fr[i] = srcF[i * 512 + tid];
    }
    float vh[4][8];
    loadrow(xl + (size_t)arow * D + g * 8, vh);

    #pragma unroll
    for (int ks = 0; ks < 4; ks++)
        #pragma unroll
        for (int nn = 0; nn < 4; nn++)
            mm2(acc[nn], ah[ks], al[ks], lds, (((nbase + nn) * 4 + ks) * 64 + lane) * 8);

    __syncthreads();                                   // b2: msg reads of buf0 done
    {
        short8v* d0 = (short8v*)lds;
        #pragma unroll
        for (int i = 0; i < 4; i++) d0[i * 512 + tid] = fr[i];
    }
    #pragma unroll
    for (int ks = 0; ks < 4; ks++) cvt_frag(vh[ks], ah[ks], al[ks]);

    float vf[4][8];
    loadrow(xl + (size_t)(arow ^ 256) * D + g * 8, vf);

    #pragma unroll
    for (int ks = 0; ks < 4; ks++)
        #pragma unroll
        for (int nn = 0; nn < 4; nn++)
            mm2(acc[nn], ah[ks], al[ks], lds + PKM, (((nbase + nn) * 4 + ks) * 64 + lane) * 8);

    __syncthreads();                                   // b3: flip staged & visible
    #pragma unroll
    for (int ks = 0; ks < 4; ks++) cvt_frag(vf[ks], ah[ks], al[ks]);
    #pragma unroll
    for (int ks = 0; ks < 4; ks++)
        #pragma unroll
        for (int nn = 0; nn < 4; nn++)
            mm2(acc[nn], ah[ks], al[ks], lds, (((nbase + nn) * 4 + ks) * 64 + lane) * 8);

    float bias[4], tvv[4], vwv[4];
    #pragma unroll
    for (int nn = 0; nn < 4; nn++) {
        int n = nbase + nn;
        bias[nn] = bih[n * 16 + m] + bhh[n * 16 + m];
        tvv[nn] = tv[n * 16 + m];
        vwv[nn] = vote ? vw[n * 16 + m] : 0.f;
    }
    float wv[4][4];
    #pragma unroll
    for (int r = 0; r < 4; r++) {
        float ssp = 0.f, twp = 0.f, vwp = 0.f;
        #pragma unroll
        for (int nn = 0; nn < 4; nn++) {
            float w = ftanh(acc[nn][r] + bias[nn]);
            wv[r][nn] = w;
            ssp += w * w; twp += w * tvv[nn]; vwp += w * vwv[nn];
        }
        ssp += __shfl_xor(ssp, 1); ssp += __shfl_xor(ssp, 2);
        ssp += __shfl_xor(ssp, 4); ssp += __shfl_xor(ssp, 8);
        twp += __shfl_xor(twp, 1); twp += __shfl_xor(twp, 2);
        twp += __shfl_xor(twp, 4); twp += __shfl_xor(twp, 8);
        if (vote) {
            vwp += __shfl_xor(vwp, 1); vwp += __shfl_xor(vwp, 2);
            vwp += __shfl_xor(vwp, 4); vwp += __shfl_xor(vwp, 8);
        }
        if (m == 0) {
            int rl = rw * 16 + g * 4 + r;
            ssx[rl * 2 + nh] = ssp;
            twx[rl * 2 + nh] = twp;
            if (vote) vwx[rl * 2 + nh] = vwp;
        }
    }
    __syncthreads();                                   // b4
    const float vb0 = vote ? vb[0] : 0.f;
    #pragma unroll
    for (int r = 0; r < 4; r++) {
        const int rl = rw * 16 + g * 4 + r;
        const int grow = lbase + perm[lbase + rl];
        const float ss = ssx[rl * 2] + ssx[rl * 2 + 1];
        const float rn = __builtin_amdgcn_rsqf(ss);
        const size_t rowoff = (size_t)grow * D + m;
        #pragma unroll
        for (int nn = 0; nn < 4; nn++)
            xl_out[rowoff + (nbase + nn) * 16] = wv[r][nn] * rn;
        if (m == 0 && nh == 0) {
            const float td = rn * (twx[rl * 2] + twx[rl * 2 + 1]);
            truth[grow] = td;
            if (truth2) truth2[grow] = td;
            if (vote) vote[grow] = rn * (vwx[rl * 2] + vwx[rl * 2 + 1]) + vb0;
        }
    }
}

// ---------------- mean-pool --------------------------------------------------
__global__ void pool_kernel(const float* __restrict__ votes, float* __restrict__ pool) {
    __shared__ float s[4];
    int g = blockIdx.x, t = threadIdx.x;
    float v = votes[g * LITS_PER + t] + votes[g * LITS_PER + 256 + t];
    #pragma unroll
    for (int m = 32; m; m >>= 1) v += __shfl_xor(v, m);
    if ((t & 63) == 0) s[t >> 6] = v;
    __syncthreads();
    if (t == 0) pool[g] = (s[0] + s[1] + s[2] + s[3]) * (1.0f / LITS_PER);
}

// ---------------- launch ----------------------------------------------------
extern "C" void kernel_launch(void* const* d_in, const int* in_sizes, int n_in,
                              void* d_out, int out_size, void* d_ws, size_t ws_size,
                              hipStream_t stream) {
    const int*   edge_lit = (const int*)d_in[1];
    const float* x_l0     = (const float*)d_in[2];
    const float* x_c0     = (const float*)d_in[3];
    const float* W_ih_lc  = (const float*)d_in[4];
    const float* W_hh_lc  = (const float*)d_in[5];
    const float* b_ih_lc  = (const float*)d_in[6];
    const float* b_hh_lc  = (const float*)d_in[7];
    const float* W_ih_cl  = (const float*)d_in[8];
    const float* W_hh_cl  = (const float*)d_in[9];
    const float* b_ih_cl  = (const float*)d_in[10];
    const float* b_hh_cl  = (const float*)d_in[11];
    const float* L_vote_w = (const float*)d_in[12];
    const float* L_vote_b = (const float*)d_in[13];
    const float* true_vec = (const float*)d_in[14];
    // d_in[15] = num_iters (=8, compile-time T)

    float* out   = (float*)d_out;
    float* xl_o  = out + OFF_XL;
    float* call  = out + OFF_CALL;
    float* tall  = out + OFF_TALL;

    // workspace
    float* norms  = (float*)d_ws;                                   // NC
    float* xl_ws  = norms + NC;                                     // NL*D
    unsigned short* pk = (unsigned short*)(xl_ws + (size_t)NL * D); // PK_TOT
    int* counts = (int*)(pk + PK_TOT);                              // NL
    int* offs   = counts + NL;                                      // NL+1
    int* cursor = offs + NL + 1;                                    // NL
    int* csr    = cursor + NL;                                      // NE
    int* perm   = csr + NE;                                         // NL

    hipMemsetAsync(counts, 0, NL * sizeof(int), stream);

    pack5<<<PK_TOT / 256, 256, 0, stream>>>(W_ih_lc, W_hh_lc, W_hh_cl, W_ih_cl, pk);
    csr_count<<<NE / 256, 256, 0, stream>>>(edge_lit, counts);
    csr_scan<<<1, 1024, 0, stream>>>(counts, offs, cursor);
    csr_fill<<<NE / 256, 256, 0, stream>>>(edge_lit, cursor, csr);
    csr_sort<<<NL / 256, 256, 0, stream>>>(offs, csr);
    make_perm<<<NL / 64, 64, 0, stream>>>(counts, perm);

    rownorm_dot<<<NL / 4, 256, 0, stream>>>(x_l0, xl_o, true_vec, tall, out + OFF_T0, NL);
    rownorm_dot<<<NC / 4, 256, 0, stream>>>(x_c0, call, nullptr, nullptr, nullptr, NC);

    for (int t = 1; t <= T; t++) {
        const float* xl_src = (t & 1) ? xl_o : xl_ws;   // ping-pong; T even ends in xl_o
        float*       xl_dst = (t & 1) ? xl_ws : xl_o;
        lc_mfma<<<NC / 128, 512, SHM_LC, stream>>>(
            edge_lit, xl_src, call + (size_t)(t - 1) * NC * D, pk,
            b_ih_lc, b_hh_lc, call + (size_t)t * NC * D, norms);
        cl_mfma<<<NL / 64, 512, SHM_CL, stream>>>(
            offs, csr, perm, call + (size_t)t * NC * D, norms, xl_src, pk,
            b_ih_cl, b_hh_cl, true_vec, L_vote_w, L_vote_b,
            xl_dst, tall + (size_t)t * NL,
            (t == T) ? out + OFF_TLAST : nullptr,
            (t == T) ? out + OFF_VOTE : nullptr);
    }

    pool_kernel<<<Bg, 256, 0, stream>>>(out + OFF_VOTE, out + OFF_POOL);
}

// Round 9
// 564.372 us; speedup vs baseline: 2.7041x; 1.1876x over previous
//
#include <hip/hip_runtime.h>
#include <math.h>

// NeuroSAT RNN forward on MI355X — multi-kernel, MFMA bf16x2, weights LDS-staged,
// bf16 shadow state for scattered gathers (xc_bf pre-norm, xl_bf normalized).
namespace {
constexpr int NVARS    = 256;
constexpr int LITS_PER = 2 * NVARS;     // 512
constexpr int Bg       = 64;            // graphs
constexpr int NL       = Bg * LITS_PER; // 32768 literals
constexpr int CLS_PER  = 1024;
constexpr int NC       = Bg * CLS_PER;  // 65536 clauses
constexpr int NE       = NC * 3;        // 196608 edges (K=3)
constexpr int D        = 128;
constexpr int T        = 8;             // num_iters (fixed scalar input)

// d_out flat layout (reference tuple order)
constexpr size_t OFF_VOTE  = 0;                                  // [NL]
constexpr size_t OFF_XL    = (size_t)NL;                         // [NL*D]   (x_l state)
constexpr size_t OFF_POOL  = OFF_XL + (size_t)NL * D;            // [Bg]
constexpr size_t OFF_TLAST = OFF_POOL + Bg;                      // [NL]
constexpr size_t OFF_TALL  = OFF_TLAST + NL;                     // [(T+1)*NL]
constexpr size_t OFF_CALL  = OFF_TALL + (size_t)(T + 1) * NL;    // [(T+1)*NC*D] (x_c state)
constexpr size_t OFF_T0    = OFF_CALL + (size_t)(T + 1) * NC * D;// [NL]

// packed weights, single bf16 plane per matrix, frag order [n][ks][lane][8]:
// 0: W_ih_lc | 1: W_hh_lc | 2: W_hh_cl | 3: W_ih_cl[:, :128] | 4: W_ih_cl[:, 128:]
constexpr int PKM    = 16384;           // ushorts per matrix
constexpr int PK_TOT = 5 * PKM;         // 81920
constexpr size_t SHM_LC = 2 * PKM * sizeof(unsigned short);          // 64 KB
constexpr size_t SHM_CL = 2 * PKM * sizeof(unsigned short) + 1536;   // 64 KB + scratch
} // namespace

typedef __attribute__((ext_vector_type(8))) short short8v;
typedef __attribute__((ext_vector_type(4))) float f32x4;

__device__ __forceinline__ unsigned short f2bf(float v) {
    unsigned u = __float_as_uint(v);
    return (unsigned short)((u + 0x7fffu + ((u >> 16) & 1u)) >> 16);  // RNE
}
__device__ __forceinline__ float bf2f(unsigned short b) {
    return __uint_as_float(((unsigned)b) << 16);
}
__device__ __forceinline__ void cvt_frag(const float (&v)[8], short8v& ah, short8v& al) {
    #pragma unroll
    for (int j = 0; j < 8; j++) {
        unsigned short h = f2bf(v[j]);
        ah[j] = (short)h;
        al[j] = (short)f2bf(v[j] - bf2f(h));
    }
}
__device__ __forceinline__ float ftanh(float x) {
    float e = __builtin_amdgcn_exp2f(x * 2.885390081777926814f);
    return 1.0f - 2.0f * __builtin_amdgcn_rcpf(e + 1.0f);
}
// bf16x2: A split (ah+al), B single bf16 plane from LDS. 2 MFMAs, 1 LDS read.
__device__ __forceinline__ void mm2(f32x4& c, short8v ah, short8v al,
                                    const unsigned short* buf, int off) {
    short8v b = *(const short8v*)(buf + off);
    c = __builtin_amdgcn_mfma_f32_16x16x32_bf16(ah, b, c, 0, 0, 0);
    c = __builtin_amdgcn_mfma_f32_16x16x32_bf16(al, b, c, 0, 0, 0);
}

// ---------------- W packing (single plane) -----------------------------------
__global__ __launch_bounds__(256) void pack5(
    const float* __restrict__ ihlc, const float* __restrict__ hhlc,
    const float* __restrict__ hhcl, const float* __restrict__ ihcl,
    unsigned short* __restrict__ pk) {
    int idx = blockIdx.x * 256 + threadIdx.x;
    int mat = idx >> 14, rel = idx & 16383;
    int j = rel & 7, lane = (rel >> 3) & 63, ks = (rel >> 9) & 3, n = rel >> 11;
    int r = n * 16 + (lane & 15);
    int k = ks * 32 + (lane >> 4) * 8 + j;
    float w;
    if (mat == 0)      w = ihlc[r * 128 + k];
    else if (mat == 1) w = hhlc[r * 128 + k];
    else if (mat == 2) w = hhcl[r * 128 + k];
    else if (mat == 3) w = ihcl[r * 256 + k];
    else               w = ihcl[r * 256 + 128 + k];
    pk[mat * PKM + rel] = f2bf(w);
}

// ---------------- CSR build --------------------------------------------------
__global__ void csr_count(const int* __restrict__ edge_lit, int* __restrict__ counts) {
    int e = blockIdx.x * blockDim.x + threadIdx.x;
    if (e < NE) atomicAdd(&counts[edge_lit[e]], 1);
}

__global__ __launch_bounds__(1024) void csr_scan(const int* __restrict__ counts,
                                                 int* __restrict__ offs,
                                                 int* __restrict__ cursor) {
    __shared__ int part[1024];
    const int t = threadIdx.x;
    const int base = t * 32;
    int local[32];
    int s = 0;
    for (int i = 0; i < 32; i++) { local[i] = s; s += counts[base + i]; }
    part[t] = s;
    __syncthreads();
    for (int d = 1; d < 1024; d <<= 1) {
        int v = 0;
        if (t >= d) v = part[t - d];
        __syncthreads();
        if (t >= d) part[t] += v;
        __syncthreads();
    }
    const int excl = (t == 0) ? 0 : part[t - 1];
    for (int i = 0; i < 32; i++) {
        int o = excl + local[i];
        offs[base + i] = o;
        cursor[base + i] = o;
    }
    if (t == 1023) offs[NL] = part[1023];
}

__global__ void csr_fill(const int* __restrict__ edge_lit, int* __restrict__ cursor,
                         int* __restrict__ csr) {
    int e = blockIdx.x * blockDim.x + threadIdx.x;
    if (e < NE) {
        int l = edge_lit[e];
        int p = atomicAdd(&cursor[l], 1);
        csr[p] = e / 3;
    }
}

__global__ void csr_sort(const int* __restrict__ offs, int* __restrict__ csr) {
    int l = blockIdx.x * blockDim.x + threadIdx.x;
    if (l >= NL) return;
    int s = offs[l], e = offs[l + 1];
    for (int i = s + 1; i < e; i++) {
        int v = csr[i];
        int j = i - 1;
        while (j >= s && csr[j] > v) { csr[j + 1] = csr[j]; j--; }
        csr[j + 1] = v;
    }
}

// per-64-literal-group degree sort (stable) -> perm of local indices
__global__ __launch_bounds__(64) void make_perm(const int* __restrict__ counts,
                                                int* __restrict__ perm) {
    __shared__ int d[64];
    const int b = blockIdx.x, i = threadIdx.x;
    d[i] = counts[b * 64 + i];
    __syncthreads();
    const int di = d[i];
    int rank = 0;
    for (int j = 0; j < 64; j++) {
        int dj = d[j];
        rank += (dj < di) || (dj == di && j < i);
    }
    perm[b * 64 + rank] = i;
}

// ---------------- init: row L2-normalize (+ fused dot, + bf16 shadow) --------
__global__ void rownorm_dot(const float* __restrict__ in, float* __restrict__ out,
                            unsigned short* __restrict__ out_bf,
                            const float* __restrict__ dotw, float* __restrict__ dot0,
                            float* __restrict__ dot1, int nrows) {
    int wave = (int)((blockIdx.x * blockDim.x + threadIdx.x) >> 6);
    int lane = threadIdx.x & 63;
    if (wave >= nrows) return;
    const float* r = in + (size_t)wave * D;
    float v0 = r[lane], v1 = r[lane + 64];
    float ss = v0 * v0 + v1 * v1;
    #pragma unroll
    for (int m = 32; m; m >>= 1) ss += __shfl_xor(ss, m);
    float rn = 1.0f / sqrtf(ss);
    float y0 = v0 * rn, y1 = v1 * rn;
    float* o = out + (size_t)wave * D;
    o[lane] = y0;
    o[lane + 64] = y1;
    if (out_bf) {
        unsigned short* ob = out_bf + (size_t)wave * D;
        ob[lane] = f2bf(y0);
        ob[lane + 64] = f2bf(y1);
    }
    if (dotw) {
        float dv = y0 * dotw[lane] + y1 * dotw[lane + 64];
        #pragma unroll
        for (int m = 32; m; m >>= 1) dv += __shfl_xor(dv, m);
        if (lane == 0) {
            dot0[wave] = dv;
            if (dot1) dot1[wave] = dv;
        }
    }
}

// -------- gather helpers (bf16 sources) --------------------------------------
__device__ __forceinline__ void gather3b(const int* __restrict__ ep,
                                         const unsigned short* __restrict__ xlb,
                                         int arow, int g, float (&v)[4][8]) {
    int e0 = ep[3 * arow], e1 = ep[3 * arow + 1], e2 = ep[3 * arow + 2];
    const unsigned short* r0 = xlb + (size_t)e0 * D + g * 8;
    const unsigned short* r1 = xlb + (size_t)e1 * D + g * 8;
    const unsigned short* r2 = xlb + (size_t)e2 * D + g * 8;
    #pragma unroll
    for (int ks = 0; ks < 4; ks++) {
        short8v a = *(const short8v*)(r0 + ks * 32);
        short8v b = *(const short8v*)(r1 + ks * 32);
        short8v c = *(const short8v*)(r2 + ks * 32);
        #pragma unroll
        for (int j = 0; j < 8; j++)
            v[ks][j] = bf2f((unsigned short)a[j]) + bf2f((unsigned short)b[j]) +
                       bf2f((unsigned short)c[j]);
    }
}

__device__ __forceinline__ void loadrow(const float* __restrict__ rp, float (&v)[4][8]) {
    #pragma unroll
    for (int ks = 0; ks < 4; ks++) {
        float4 a = *(const float4*)(rp + ks * 32), b = *(const float4*)(rp + ks * 32 + 4);
        v[ks][0] = a.x; v[ks][1] = a.y; v[ks][2] = a.z; v[ks][3] = a.w;
        v[ks][4] = b.x; v[ks][5] = b.y; v[ks][6] = b.z; v[ks][7] = b.w;
    }
}

__device__ __forceinline__ void gatherCSRb(const int* __restrict__ offs,
                                           const int* __restrict__ csr,
                                           const unsigned short* __restrict__ xcb,
                                           int arow, int g, float (&v)[4][8]) {
    #pragma unroll
    for (int ks = 0; ks < 4; ks++)
        #pragma unroll
        for (int j = 0; j < 8; j++) v[ks][j] = 0.f;
    const int s = offs[arow], e = offs[arow + 1];
    for (int p = s; p < e; p++) {
        const unsigned short* q = xcb + (size_t)csr[p] * D + g * 8;
        #pragma unroll
        for (int ks = 0; ks < 4; ks++) {
            short8v a = *(const short8v*)(q + ks * 32);
            #pragma unroll
            for (int j = 0; j < 8; j++) v[ks][j] += bf2f((unsigned short)a[j]);
        }
    }
}

// ---------------- LC: 512 blocks x 512 thr; 128 rows/block; wave=16 rows -----
__global__ __launch_bounds__(512, 4) void lc_mfma(
    const int* __restrict__ edge_lit, const unsigned short* __restrict__ xl_bf,
    const float* __restrict__ xc_prev, const unsigned short* __restrict__ pk,
    const float* __restrict__ bih, const float* __restrict__ bhh,
    float* __restrict__ xc_norm, unsigned short* __restrict__ xc_bf) {
    extern __shared__ __align__(16) unsigned short lds[];  // [0,PKM)=ih, [PKM,2PKM)=hh
    const int tid = threadIdx.x, wid = tid >> 6, lane = tid & 63;
    const int m = lane & 15, g = lane >> 4;
    const int p = blockIdx.x;
    const int blk = (p & 7) * 64 + (p >> 3);    // XCD-chunked, grid=512 bijective
    const int rowbase = blk * 128;
    const int arow = rowbase + wid * 16 + m;

    // stage ih_lc + hh_lc (64 KB contiguous in pk)
    {
        const short8v* src = (const short8v*)pk;
        short8v* dst = (short8v*)lds;
        #pragma unroll
        for (int i = 0; i < 8; i++) dst[i * 512 + tid] = src[i * 512 + tid];
    }
    float v[4][8];
    gather3b(edge_lit, xl_bf, arow, g, v);
    float vh[4][8];
    loadrow(xc_prev + (size_t)arow * D + g * 8, vh);
    __syncthreads();

    short8v ah[4], al[4];
    #pragma unroll
    for (int ks = 0; ks < 4; ks++) cvt_frag(v[ks], ah[ks], al[ks]);

    f32x4 acc[8];
    #pragma unroll
    for (int n = 0; n < 8; n++) acc[n] = (f32x4)0.f;

    #pragma unroll
    for (int ks = 0; ks < 4; ks++)
        #pragma unroll
        for (int n = 0; n < 8; n++)
            mm2(acc[n], ah[ks], al[ks], lds, ((n * 4 + ks) * 64 + lane) * 8);

    #pragma unroll
    for (int ks = 0; ks < 4; ks++) cvt_frag(vh[ks], ah[ks], al[ks]);
    #pragma unroll
    for (int ks = 0; ks < 4; ks++)
        #pragma unroll
        for (int n = 0; n < 8; n++)
            mm2(acc[n], ah[ks], al[ks], lds + PKM, ((n * 4 + ks) * 64 + lane) * 8);

    float bias[8];
    #pragma unroll
    for (int n = 0; n < 8; n++) bias[n] = bih[n * 16 + m] + bhh[n * 16 + m];

    const int obase = rowbase + wid * 16 + g * 4;
    #pragma unroll
    for (int r = 0; r < 4; r++) {
        float w[8], ss = 0.f;
        #pragma unroll
        for (int n = 0; n < 8; n++) { w[n] = ftanh(acc[n][r] + bias[n]); ss += w[n] * w[n]; }
        ss += __shfl_xor(ss, 1); ss += __shfl_xor(ss, 2);
        ss += __shfl_xor(ss, 4); ss += __shfl_xor(ss, 8);
        const float rn = __builtin_amdgcn_rsqf(ss);
        const size_t rowoff = (size_t)(obase + r) * D + m;
        #pragma unroll
        for (int n = 0; n < 8; n++) {
            xc_norm[rowoff + n * 16] = w[n] * rn;      // normalized (output slice)
            xc_bf[rowoff + n * 16] = f2bf(w[n]);       // pre-norm bf16 (CL gather)
        }
    }
}

// ------- CL: 512 blocks x 512 thr; 64 rows/block; wave=16 rows x N-half ------
__global__ __launch_bounds__(512, 4) void cl_mfma(
    const int* __restrict__ offs, const int* __restrict__ csr,
    const int* __restrict__ perm,
    const unsigned short* __restrict__ xc_bf,
    const float* __restrict__ xl, const unsigned short* __restrict__ pk,
    const float* __restrict__ bih, const float* __restrict__ bhh,
    const float* __restrict__ tv, const float* __restrict__ vw,
    const float* __restrict__ vb,
    float* __restrict__ xl_out, unsigned short* __restrict__ xl_bf,
    float* __restrict__ truth, float* __restrict__ truth2, float* __restrict__ vote) {
    extern __shared__ __align__(16) unsigned short lds[];
    // buf0 [0,PKM): ih_msg -> later ih_flip ; buf1 [PKM,2PKM): hh
    float* scr = (float*)(lds + 2 * PKM);
    float* ssx = scr; float* twx = scr + 128; float* vwx = scr + 256;

    const int tid = threadIdx.x, wid = tid >> 6, lane = tid & 63;
    const int m = lane & 15, g = lane >> 4;
    const int rw = wid >> 1, nh = wid & 1, nbase = nh * 4;
    const int p0 = blockIdx.x;
    const int blk = (p0 & 7) * 64 + (p0 >> 3);
    const int lbase = blk * 64;
    const int arow = lbase + perm[lbase + rw * 16 + m];

    // stage buf0=ih_msg (mat3), buf1=hh (mat2)
    {
        const short8v* srcA = (const short8v*)(pk + 3 * PKM);
        const short8v* srcB = (const short8v*)(pk + 2 * PKM);
        short8v* d0 = (short8v*)lds;
        short8v* d1 = (short8v*)(lds + PKM);
        #pragma unroll
        for (int i = 0; i < 4; i++) d0[i * 512 + tid] = srcA[i * 512 + tid];
        #pragma unroll
        for (int i = 0; i < 4; i++) d1[i * 512 + tid] = srcB[i * 512 + tid];
    }
    float v[4][8];
    gatherCSRb(offs, csr, xc_bf, arow, g, v);
    __syncthreads();                                   // b1

    short8v ah[4], al[4];
    #pragma unroll
    for (int ks = 0; ks < 4; ks++) cvt_frag(v[ks], ah[ks], al[ks]);

    f32x4 acc[4];
    #pragma unroll
    for (int n = 0; n < 4; n++) acc[n] = (f32x4)0.f;

    // T14 split: issue flip-W prefetch + hidden-row loads before msg MFMAs
    short8v fr[4];
    {
        const short8v* srcF = (const short8v*)(pk + 4 * PKM);  // ih_flip
        #pragma unroll
        for (int i = 0; i < 4; i++) fr[i] = srcF[i * 512 + tid];
    }
    float vh[4][8];
    loadrow(xl + (size_t)arow * D + g * 8, vh);

    #pragma unroll
    for (int ks = 0; ks < 4; ks++)
        #pragma unroll
        for (int nn = 0; nn < 4; nn++)
            mm2(acc[nn], ah[ks], al[ks], lds, (((nbase + nn) * 4 + ks) * 64 + lane) * 8);

    __syncthreads();                                   // b2: msg reads of buf0 done
    {
        short8v* d0 = (short8v*)lds;
        #pragma unroll
        for (int i = 0; i < 4; i++) d0[i * 512 + tid] = fr[i];
    }
    #pragma unroll
    for (int ks = 0; ks < 4; ks++) cvt_frag(vh[ks], ah[ks], al[ks]);

    float vf[4][8];
    loadrow(xl + (size_t)(arow ^ 256) * D + g * 8, vf);

    #pragma unroll
    for (int ks = 0; ks < 4; ks++)
        #pragma unroll
        for (int nn = 0; nn < 4; nn++)
            mm2(acc[nn], ah[ks], al[ks], lds + PKM, (((nbase + nn) * 4 + ks) * 64 + lane) * 8);

    __syncthreads();                                   // b3: flip staged & visible
    #pragma unroll
    for (int ks = 0; ks < 4; ks++) cvt_frag(vf[ks], ah[ks], al[ks]);
    #pragma unroll
    for (int ks = 0; ks < 4; ks++)
        #pragma unroll
        for (int nn = 0; nn < 4; nn++)
            mm2(acc[nn], ah[ks], al[ks], lds, (((nbase + nn) * 4 + ks) * 64 + lane) * 8);

    float bias[4], tvv[4], vwv[4];
    #pragma unroll
    for (int nn = 0; nn < 4; nn++) {
        int n = nbase + nn;
        bias[nn] = bih[n * 16 + m] + bhh[n * 16 + m];
        tvv[nn] = tv[n * 16 + m];
        vwv[nn] = vote ? vw[n * 16 + m] : 0.f;
    }
    float wv[4][4];
    #pragma unroll
    for (int r = 0; r < 4; r++) {
        float ssp = 0.f, twp = 0.f, vwp = 0.f;
        #pragma unroll
        for (int nn = 0; nn < 4; nn++) {
            float w = ftanh(acc[nn][r] + bias[nn]);
            wv[r][nn] = w;
            ssp += w * w; twp += w * tvv[nn]; vwp += w * vwv[nn];
        }
        ssp += __shfl_xor(ssp, 1); ssp += __shfl_xor(ssp, 2);
        ssp += __shfl_xor(ssp, 4); ssp += __shfl_xor(ssp, 8);
        twp += __shfl_xor(twp, 1); twp += __shfl_xor(twp, 2);
        twp += __shfl_xor(twp, 4); twp += __shfl_xor(twp, 8);
        if (vote) {
            vwp += __shfl_xor(vwp, 1); vwp += __shfl_xor(vwp, 2);
            vwp += __shfl_xor(vwp, 4); vwp += __shfl_xor(vwp, 8);
        }
        if (m == 0) {
            int rl = rw * 16 + g * 4 + r;
            ssx[rl * 2 + nh] = ssp;
            twx[rl * 2 + nh] = twp;
            if (vote) vwx[rl * 2 + nh] = vwp;
        }
    }
    __syncthreads();                                   // b4
    const float vb0 = vote ? vb[0] : 0.f;
    #pragma unroll
    for (int r = 0; r < 4; r++) {
        const int rl = rw * 16 + g * 4 + r;
        const int grow = lbase + perm[lbase + rl];
        const float ss = ssx[rl * 2] + ssx[rl * 2 + 1];
        const float rn = __builtin_amdgcn_rsqf(ss);
        const size_t rowoff = (size_t)grow * D + m;
        #pragma unroll
        for (int nn = 0; nn < 4; nn++) {
            const float y = wv[r][nn] * rn;
            xl_out[rowoff + (nbase + nn) * 16] = y;
            xl_bf[rowoff + (nbase + nn) * 16] = f2bf(y);   // shadow for next LC gather
        }
        if (m == 0 && nh == 0) {
            const float td = rn * (twx[rl * 2] + twx[rl * 2 + 1]);
            truth[grow] = td;
            if (truth2) truth2[grow] = td;
            if (vote) vote[grow] = rn * (vwx[rl * 2] + vwx[rl * 2 + 1]) + vb0;
        }
    }
}

// ---------------- mean-pool --------------------------------------------------
__global__ void pool_kernel(const float* __restrict__ votes, float* __restrict__ pool) {
    __shared__ float s[4];
    int g = blockIdx.x, t = threadIdx.x;
    float v = votes[g * LITS_PER + t] + votes[g * LITS_PER + 256 + t];
    #pragma unroll
    for (int m = 32; m; m >>= 1) v += __shfl_xor(v, m);
    if ((t & 63) == 0) s[t >> 6] = v;
    __syncthreads();
    if (t == 0) pool[g] = (s[0] + s[1] + s[2] + s[3]) * (1.0f / LITS_PER);
}

// ---------------- launch ----------------------------------------------------
extern "C" void kernel_launch(void* const* d_in, const int* in_sizes, int n_in,
                              void* d_out, int out_size, void* d_ws, size_t ws_size,
                              hipStream_t stream) {
    const int*   edge_lit = (const int*)d_in[1];
    const float* x_l0     = (const float*)d_in[2];
    const float* x_c0     = (const float*)d_in[3];
    const float* W_ih_lc  = (const float*)d_in[4];
    const float* W_hh_lc  = (const float*)d_in[5];
    const float* b_ih_lc  = (const float*)d_in[6];
    const float* b_hh_lc  = (const float*)d_in[7];
    const float* W_ih_cl  = (const float*)d_in[8];
    const float* W_hh_cl  = (const float*)d_in[9];
    const float* b_ih_cl  = (const float*)d_in[10];
    const float* b_hh_cl  = (const float*)d_in[11];
    const float* L_vote_w = (const float*)d_in[12];
    const float* L_vote_b = (const float*)d_in[13];
    const float* true_vec = (const float*)d_in[14];
    // d_in[15] = num_iters (=8, compile-time T)

    float* out   = (float*)d_out;
    float* xl_o  = out + OFF_XL;
    float* call  = out + OFF_CALL;
    float* tall  = out + OFF_TALL;

    // workspace (16B-aligned slices)
    float* xl_ws = (float*)d_ws;                                       // NL*D f32
    unsigned short* xc_bf = (unsigned short*)(xl_ws + (size_t)NL * D); // NC*D bf16
    unsigned short* xl_bf = xc_bf + (size_t)NC * D;                    // NL*D bf16
    unsigned short* pk = xl_bf + (size_t)NL * D;                       // PK_TOT
    int* counts = (int*)(pk + PK_TOT);                                 // NL
    int* offs   = counts + NL;                                         // NL+1
    int* cursor = offs + NL + 1;                                       // NL
    int* csr    = cursor + NL;                                         // NE
    int* perm   = csr + NE;                                            // NL

    hipMemsetAsync(counts, 0, NL * sizeof(int), stream);

    pack5<<<PK_TOT / 256, 256, 0, stream>>>(W_ih_lc, W_hh_lc, W_hh_cl, W_ih_cl, pk);
    csr_count<<<NE / 256, 256, 0, stream>>>(edge_lit, counts);
    csr_scan<<<1, 1024, 0, stream>>>(counts, offs, cursor);
    csr_fill<<<NE / 256, 256, 0, stream>>>(edge_lit, cursor, csr);
    csr_sort<<<NL / 256, 256, 0, stream>>>(offs, csr);
    make_perm<<<NL / 64, 64, 0, stream>>>(counts, perm);

    rownorm_dot<<<NL / 4, 256, 0, stream>>>(x_l0, xl_o, xl_bf, true_vec, tall,
                                            out + OFF_T0, NL);
    rownorm_dot<<<NC / 4, 256, 0, stream>>>(x_c0, call, nullptr, nullptr, nullptr,
                                            nullptr, NC);

    for (int t = 1; t <= T; t++) {
        const float* xl_src = (t & 1) ? xl_o : xl_ws;   // ping-pong; T even ends in xl_o
        float*       xl_dst = (t & 1) ? xl_ws : xl_o;
        lc_mfma<<<NC / 128, 512, SHM_LC, stream>>>(
            edge_lit, xl_bf, call + (size_t)(t - 1) * NC * D, pk,
            b_ih_lc, b_hh_lc, call + (size_t)t * NC * D, xc_bf);
        cl_mfma<<<NL / 64, 512, SHM_CL, stream>>>(
            offs, csr, perm, xc_bf, xl_src, pk,
            b_ih_cl, b_hh_cl, true_vec, L_vote_w, L_vote_b,
            xl_dst, xl_bf, tall + (size_t)t * NL,
            (t == T) ? out + OFF_TLAST : nullptr,
            (t == T) ? out + OFF_VOTE : nullptr);
    }

    pool_kernel<<<Bg, 256, 0, stream>>>(out + OFF_VOTE, out + OFF_POOL);
}

// Round 10
// 510.028 us; speedup vs baseline: 2.9922x; 1.1066x over previous
//
#include <hip/hip_runtime.h>
#include <math.h>

// NeuroSAT RNN forward on MI355X — MFMA, weights LDS-staged, full bf16 shadow
// state: xc_bf (pre-norm), xl_bf ping-pong (normalized). f32 xl written only at T.
namespace {
constexpr int NVARS    = 256;
constexpr int LITS_PER = 2 * NVARS;     // 512
constexpr int Bg       = 64;            // graphs
constexpr int NL       = Bg * LITS_PER; // 32768 literals
constexpr int CLS_PER  = 1024;
constexpr int NC       = Bg * CLS_PER;  // 65536 clauses
constexpr int NE       = NC * 3;        // 196608 edges (K=3)
constexpr int D        = 128;
constexpr int T        = 8;             // num_iters (fixed scalar input)

// d_out flat layout (reference tuple order)
constexpr size_t OFF_VOTE  = 0;                                  // [NL]
constexpr size_t OFF_XL    = (size_t)NL;                         // [NL*D]   (x_l state)
constexpr size_t OFF_POOL  = OFF_XL + (size_t)NL * D;            // [Bg]
constexpr size_t OFF_TLAST = OFF_POOL + Bg;                      // [NL]
constexpr size_t OFF_TALL  = OFF_TLAST + NL;                     // [(T+1)*NL]
constexpr size_t OFF_CALL  = OFF_TALL + (size_t)(T + 1) * NL;    // [(T+1)*NC*D] (x_c state)
constexpr size_t OFF_T0    = OFF_CALL + (size_t)(T + 1) * NC * D;// [NL]

// packed weights, single bf16 plane per matrix, frag order [n][ks][lane][8]:
// 0: W_ih_lc | 1: W_hh_lc | 2: W_hh_cl | 3: W_ih_cl[:, :128] | 4: W_ih_cl[:, 128:]
constexpr int PKM    = 16384;           // ushorts per matrix
constexpr int PK_TOT = 5 * PKM;         // 81920
constexpr size_t SHM_LC = 2 * PKM * sizeof(unsigned short);          // 64 KB
constexpr size_t SHM_CL = 2 * PKM * sizeof(unsigned short) + 1536;   // 64 KB + scratch
} // namespace

typedef __attribute__((ext_vector_type(8))) short short8v;
typedef __attribute__((ext_vector_type(4))) float f32x4;

__device__ __forceinline__ unsigned short f2bf(float v) {
    unsigned u = __float_as_uint(v);
    return (unsigned short)((u + 0x7fffu + ((u >> 16) & 1u)) >> 16);  // RNE
}
__device__ __forceinline__ float bf2f(unsigned short b) {
    return __uint_as_float(((unsigned)b) << 16);
}
__device__ __forceinline__ void cvt_frag(const float (&v)[8], short8v& ah, short8v& al) {
    #pragma unroll
    for (int j = 0; j < 8; j++) {
        unsigned short h = f2bf(v[j]);
        ah[j] = (short)h;
        al[j] = (short)f2bf(v[j] - bf2f(h));
    }
}
__device__ __forceinline__ float ftanh(float x) {
    float e = __builtin_amdgcn_exp2f(x * 2.885390081777926814f);
    return 1.0f - 2.0f * __builtin_amdgcn_rcpf(e + 1.0f);
}
// bf16x2: A split (ah+al), B single bf16 plane from LDS. 2 MFMAs, 1 LDS read.
__device__ __forceinline__ void mm2(f32x4& c, short8v ah, short8v al,
                                    const unsigned short* buf, int off) {
    short8v b = *(const short8v*)(buf + off);
    c = __builtin_amdgcn_mfma_f32_16x16x32_bf16(ah, b, c, 0, 0, 0);
    c = __builtin_amdgcn_mfma_f32_16x16x32_bf16(al, b, c, 0, 0, 0);
}
// pure-bf16 A (exact): 1 MFMA
__device__ __forceinline__ void mm1(f32x4& c, short8v a,
                                    const unsigned short* buf, int off) {
    short8v b = *(const short8v*)(buf + off);
    c = __builtin_amdgcn_mfma_f32_16x16x32_bf16(a, b, c, 0, 0, 0);
}

// ---------------- W packing (single plane) -----------------------------------
__global__ __launch_bounds__(256) void pack5(
    const float* __restrict__ ihlc, const float* __restrict__ hhlc,
    const float* __restrict__ hhcl, const float* __restrict__ ihcl,
    unsigned short* __restrict__ pk) {
    int idx = blockIdx.x * 256 + threadIdx.x;
    int mat = idx >> 14, rel = idx & 16383;
    int j = rel & 7, lane = (rel >> 3) & 63, ks = (rel >> 9) & 3, n = rel >> 11;
    int r = n * 16 + (lane & 15);
    int k = ks * 32 + (lane >> 4) * 8 + j;
    float w;
    if (mat == 0)      w = ihlc[r * 128 + k];
    else if (mat == 1) w = hhlc[r * 128 + k];
    else if (mat == 2) w = hhcl[r * 128 + k];
    else if (mat == 3) w = ihcl[r * 256 + k];
    else               w = ihcl[r * 256 + 128 + k];
    pk[mat * PKM + rel] = f2bf(w);
}

// ---------------- CSR build --------------------------------------------------
__global__ void csr_count(const int* __restrict__ edge_lit, int* __restrict__ counts) {
    int e = blockIdx.x * blockDim.x + threadIdx.x;
    if (e < NE) atomicAdd(&counts[edge_lit[e]], 1);
}

__global__ __launch_bounds__(1024) void csr_scan(const int* __restrict__ counts,
                                                 int* __restrict__ offs,
                                                 int* __restrict__ cursor) {
    __shared__ int part[1024];
    const int t = threadIdx.x;
    const int base = t * 32;
    int local[32];
    int s = 0;
    for (int i = 0; i < 32; i++) { local[i] = s; s += counts[base + i]; }
    part[t] = s;
    __syncthreads();
    for (int d = 1; d < 1024; d <<= 1) {
        int v = 0;
        if (t >= d) v = part[t - d];
        __syncthreads();
        if (t >= d) part[t] += v;
        __syncthreads();
    }
    const int excl = (t == 0) ? 0 : part[t - 1];
    for (int i = 0; i < 32; i++) {
        int o = excl + local[i];
        offs[base + i] = o;
        cursor[base + i] = o;
    }
    if (t == 1023) offs[NL] = part[1023];
}

__global__ void csr_fill(const int* __restrict__ edge_lit, int* __restrict__ cursor,
                         int* __restrict__ csr) {
    int e = blockIdx.x * blockDim.x + threadIdx.x;
    if (e < NE) {
        int l = edge_lit[e];
        int p = atomicAdd(&cursor[l], 1);
        csr[p] = e / 3;
    }
}

__global__ void csr_sort(const int* __restrict__ offs, int* __restrict__ csr) {
    int l = blockIdx.x * blockDim.x + threadIdx.x;
    if (l >= NL) return;
    int s = offs[l], e = offs[l + 1];
    for (int i = s + 1; i < e; i++) {
        int v = csr[i];
        int j = i - 1;
        while (j >= s && csr[j] > v) { csr[j + 1] = csr[j]; j--; }
        csr[j + 1] = v;
    }
}

// per-64-literal-group degree sort (stable) -> perm of local indices
__global__ __launch_bounds__(64) void make_perm(const int* __restrict__ counts,
                                                int* __restrict__ perm) {
    __shared__ int d[64];
    const int b = blockIdx.x, i = threadIdx.x;
    d[i] = counts[b * 64 + i];
    __syncthreads();
    const int di = d[i];
    int rank = 0;
    for (int j = 0; j < 64; j++) {
        int dj = d[j];
        rank += (dj < di) || (dj == di && j < i);
    }
    perm[b * 64 + rank] = i;
}

// -------- init: L2-normalize; bf shadow = normalized (norms==null) or raw+norms
__global__ void rownorm_dot(const float* __restrict__ in, float* __restrict__ out,
                            unsigned short* __restrict__ out_bf,
                            float* __restrict__ norms,
                            const float* __restrict__ dotw, float* __restrict__ dot0,
                            float* __restrict__ dot1, int nrows) {
    int wave = (int)((blockIdx.x * blockDim.x + threadIdx.x) >> 6);
    int lane = threadIdx.x & 63;
    if (wave >= nrows) return;
    const float* r = in + (size_t)wave * D;
    float v0 = r[lane], v1 = r[lane + 64];
    float ss = v0 * v0 + v1 * v1;
    #pragma unroll
    for (int m = 32; m; m >>= 1) ss += __shfl_xor(ss, m);
    float rn = 1.0f / sqrtf(ss);
    float y0 = v0 * rn, y1 = v1 * rn;
    float* o = out + (size_t)wave * D;
    o[lane] = y0;
    o[lane + 64] = y1;
    unsigned short* ob = out_bf + (size_t)wave * D;
    if (norms) {                       // store raw bf16 + row norm (x_c0 path)
        ob[lane] = f2bf(v0);
        ob[lane + 64] = f2bf(v1);
        if (lane == 0) norms[wave] = ss * rn;   // = sqrt(ss)
    } else {                           // store normalized bf16 (x_l0 path)
        ob[lane] = f2bf(y0);
        ob[lane + 64] = f2bf(y1);
    }
    if (dotw) {
        float dv = y0 * dotw[lane] + y1 * dotw[lane + 64];
        #pragma unroll
        for (int m = 32; m; m >>= 1) dv += __shfl_xor(dv, m);
        if (lane == 0) {
            dot0[wave] = dv;
            if (dot1) dot1[wave] = dv;
        }
    }
}

// -------- gather helpers (bf16 sources) --------------------------------------
__device__ __forceinline__ void gather3b(const int* __restrict__ ep,
                                         const unsigned short* __restrict__ xlb,
                                         int arow, int g, float (&v)[4][8]) {
    int e0 = ep[3 * arow], e1 = ep[3 * arow + 1], e2 = ep[3 * arow + 2];
    const unsigned short* r0 = xlb + (size_t)e0 * D + g * 8;
    const unsigned short* r1 = xlb + (size_t)e1 * D + g * 8;
    const unsigned short* r2 = xlb + (size_t)e2 * D + g * 8;
    #pragma unroll
    for (int ks = 0; ks < 4; ks++) {
        short8v a = *(const short8v*)(r0 + ks * 32);
        short8v b = *(const short8v*)(r1 + ks * 32);
        short8v c = *(const short8v*)(r2 + ks * 32);
        #pragma unroll
        for (int j = 0; j < 8; j++)
            v[ks][j] = bf2f((unsigned short)a[j]) + bf2f((unsigned short)b[j]) +
                       bf2f((unsigned short)c[j]);
    }
}

__device__ __forceinline__ void gatherCSRb(const int* __restrict__ offs,
                                           const int* __restrict__ csr,
                                           const unsigned short* __restrict__ xcb,
                                           int arow, int g, float (&v)[4][8]) {
    #pragma unroll
    for (int ks = 0; ks < 4; ks++)
        #pragma unroll
        for (int j = 0; j < 8; j++) v[ks][j] = 0.f;
    const int s = offs[arow], e = offs[arow + 1];
    for (int p = s; p < e; p++) {
        const unsigned short* q = xcb + (size_t)csr[p] * D + g * 8;
        #pragma unroll
        for (int ks = 0; ks < 4; ks++) {
            short8v a = *(const short8v*)(q + ks * 32);
            #pragma unroll
            for (int j = 0; j < 8; j++) v[ks][j] += bf2f((unsigned short)a[j]);
        }
    }
}

// ---------------- LC: 512 blocks x 512 thr; 128 rows/block; wave=16 rows -----
__global__ __launch_bounds__(512, 4) void lc_mfma(
    const int* __restrict__ edge_lit, const unsigned short* __restrict__ xl_bf,
    unsigned short* xc_bf, float* norms,          // read t-1, write t (same rows)
    const unsigned short* __restrict__ pk,
    const float* __restrict__ bih, const float* __restrict__ bhh,
    float* __restrict__ xc_norm) {
    extern __shared__ __align__(16) unsigned short lds[];  // [0,PKM)=ih, [PKM,2PKM)=hh
    const int tid = threadIdx.x, wid = tid >> 6, lane = tid & 63;
    const int m = lane & 15, g = lane >> 4;
    const int p = blockIdx.x;
    const int blk = (p & 7) * 64 + (p >> 3);    // XCD-chunked, grid=512 bijective
    const int rowbase = blk * 128;
    const int arow = rowbase + wid * 16 + m;

    // stage ih_lc + hh_lc (64 KB contiguous in pk)
    {
        const short8v* src = (const short8v*)pk;
        short8v* dst = (short8v*)lds;
        #pragma unroll
        for (int i = 0; i < 8; i++) dst[i * 512 + tid] = src[i * 512 + tid];
    }
    float v[4][8];
    gather3b(edge_lit, xl_bf, arow, g, v);
    // hidden: bf16 pre-norm row x (1/||row||); scale uniform per lane
    short8v hvb[4];
    {
        const unsigned short* hr = xc_bf + (size_t)arow * D + g * 8;
        #pragma unroll
        for (int ks = 0; ks < 4; ks++) hvb[ks] = *(const short8v*)(hr + ks * 32);
    }
    const float rnh = __builtin_amdgcn_rcpf(norms[arow]);
    __syncthreads();

    short8v ah[4], al[4];
    #pragma unroll
    for (int ks = 0; ks < 4; ks++) cvt_frag(v[ks], ah[ks], al[ks]);

    f32x4 acc[8];
    #pragma unroll
    for (int n = 0; n < 8; n++) acc[n] = (f32x4)0.f;

    #pragma unroll
    for (int ks = 0; ks < 4; ks++)
        #pragma unroll
        for (int n = 0; n < 8; n++)
            mm2(acc[n], ah[ks], al[ks], lds, ((n * 4 + ks) * 64 + lane) * 8);

    float vh[4][8];
    #pragma unroll
    for (int ks = 0; ks < 4; ks++)
        #pragma unroll
        for (int j = 0; j < 8; j++)
            vh[ks][j] = bf2f((unsigned short)hvb[ks][j]) * rnh;
    #pragma unroll
    for (int ks = 0; ks < 4; ks++) cvt_frag(vh[ks], ah[ks], al[ks]);
    #pragma unroll
    for (int ks = 0; ks < 4; ks++)
        #pragma unroll
        for (int n = 0; n < 8; n++)
            mm2(acc[n], ah[ks], al[ks], lds + PKM, ((n * 4 + ks) * 64 + lane) * 8);

    float bias[8];
    #pragma unroll
    for (int n = 0; n < 8; n++) bias[n] = bih[n * 16 + m] + bhh[n * 16 + m];

    const int obase = rowbase + wid * 16 + g * 4;
    #pragma unroll
    for (int r = 0; r < 4; r++) {
        float w[8], ss = 0.f;
        #pragma unroll
        for (int n = 0; n < 8; n++) { w[n] = ftanh(acc[n][r] + bias[n]); ss += w[n] * w[n]; }
        ss += __shfl_xor(ss, 1); ss += __shfl_xor(ss, 2);
        ss += __shfl_xor(ss, 4); ss += __shfl_xor(ss, 8);
        const float rn = __builtin_amdgcn_rsqf(ss);
        const size_t rowoff = (size_t)(obase + r) * D + m;
        #pragma unroll
        for (int n = 0; n < 8; n++) {
            xc_norm[rowoff + n * 16] = w[n] * rn;      // normalized f32 (output slice)
            xc_bf[rowoff + n * 16] = f2bf(w[n]);       // pre-norm bf16 (CL gather + next hidden)
        }
        if (m == 0) norms[obase + r] = ss * rn;        // ||row|| for next iter's hidden
    }
}

// ------- CL: 512 blocks x 512 thr; 64 rows/block; wave=16 rows x N-half ------
__global__ __launch_bounds__(512, 4) void cl_mfma(
    const int* __restrict__ offs, const int* __restrict__ csr,
    const int* __restrict__ perm,
    const unsigned short* __restrict__ xc_bf,
    const unsigned short* __restrict__ xl_src,    // bf16 normalized state (read)
    const unsigned short* __restrict__ pk,
    const float* __restrict__ bih, const float* __restrict__ bhh,
    const float* __restrict__ tv, const float* __restrict__ vw,
    const float* __restrict__ vb,
    unsigned short* __restrict__ xl_dst,          // bf16 normalized state (write)
    float* __restrict__ xl_out,                   // f32 output (t==T only, else null)
    float* __restrict__ truth, float* __restrict__ truth2, float* __restrict__ vote) {
    extern __shared__ __align__(16) unsigned short lds[];
    // buf0 [0,PKM): ih_msg -> later ih_flip ; buf1 [PKM,2PKM): hh
    float* scr = (float*)(lds + 2 * PKM);
    float* ssx = scr; float* twx = scr + 128; float* vwx = scr + 256;

    const int tid = threadIdx.x, wid = tid >> 6, lane = tid & 63;
    const int m = lane & 15, g = lane >> 4;
    const int rw = wid >> 1, nh = wid & 1, nbase = nh * 4;
    const int p0 = blockIdx.x;
    const int blk = (p0 & 7) * 64 + (p0 >> 3);
    const int lbase = blk * 64;
    const int arow = lbase + perm[lbase + rw * 16 + m];

    // stage buf0=ih_msg (mat3), buf1=hh (mat2)
    {
        const short8v* srcA = (const short8v*)(pk + 3 * PKM);
        const short8v* srcB = (const short8v*)(pk + 2 * PKM);
        short8v* d0 = (short8v*)lds;
        short8v* d1 = (short8v*)(lds + PKM);
        #pragma unroll
        for (int i = 0; i < 4; i++) d0[i * 512 + tid] = srcA[i * 512 + tid];
        #pragma unroll
        for (int i = 0; i < 4; i++) d1[i * 512 + tid] = srcB[i * 512 + tid];
    }
    float v[4][8];
    gatherCSRb(offs, csr, xc_bf, arow, g, v);
    // hidden + flip bf16 frags (exact A; issue early, land under msg MFMAs)
    short8v hv[4], fv[4];
    {
        const unsigned short* hr = xl_src + (size_t)arow * D + g * 8;
        const unsigned short* fp = xl_src + (size_t)(arow ^ 256) * D + g * 8;
        #pragma unroll
        for (int ks = 0; ks < 4; ks++) { hv[ks] = *(const short8v*)(hr + ks * 32);
                                         fv[ks] = *(const short8v*)(fp + ks * 32); }
    }
    __syncthreads();                                   // b1

    short8v ah[4], al[4];
    #pragma unroll
    for (int ks = 0; ks < 4; ks++) cvt_frag(v[ks], ah[ks], al[ks]);

    f32x4 acc[4];
    #pragma unroll
    for (int n = 0; n < 4; n++) acc[n] = (f32x4)0.f;

    // T14: prefetch flip-W to regs before msg MFMAs
    short8v fr[4];
    {
        const short8v* srcF = (const short8v*)(pk + 4 * PKM);  // ih_flip
        #pragma unroll
        for (int i = 0; i < 4; i++) fr[i] = srcF[i * 512 + tid];
    }

    #pragma unroll
    for (int ks = 0; ks < 4; ks++)
        #pragma unroll
        for (int nn = 0; nn < 4; nn++)
            mm2(acc[nn], ah[ks], al[ks], lds, (((nbase + nn) * 4 + ks) * 64 + lane) * 8);

    __syncthreads();                                   // b2: msg reads of buf0 done
    {
        short8v* d0 = (short8v*)lds;
        #pragma unroll
        for (int i = 0; i < 4; i++) d0[i * 512 + tid] = fr[i];
    }
    #pragma unroll
    for (int ks = 0; ks < 4; ks++)
        #pragma unroll
        for (int nn = 0; nn < 4; nn++)
            mm1(acc[nn], hv[ks], lds + PKM, (((nbase + nn) * 4 + ks) * 64 + lane) * 8);

    __syncthreads();                                   // b3: flip staged & visible
    #pragma unroll
    for (int ks = 0; ks < 4; ks++)
        #pragma unroll
        for (int nn = 0; nn < 4; nn++)
            mm1(acc[nn], fv[ks], lds, (((nbase + nn) * 4 + ks) * 64 + lane) * 8);

    float bias[4], tvv[4], vwv[4];
    #pragma unroll
    for (int nn = 0; nn < 4; nn++) {
        int n = nbase + nn;
        bias[nn] = bih[n * 16 + m] + bhh[n * 16 + m];
        tvv[nn] = tv[n * 16 + m];
        vwv[nn] = vote ? vw[n * 16 + m] : 0.f;
    }
    float wv[4][4];
    #pragma unroll
    for (int r = 0; r < 4; r++) {
        float ssp = 0.f, twp = 0.f, vwp = 0.f;
        #pragma unroll
        for (int nn = 0; nn < 4; nn++) {
            float w = ftanh(acc[nn][r] + bias[nn]);
            wv[r][nn] = w;
            ssp += w * w; twp += w * tvv[nn]; vwp += w * vwv[nn];
        }
        ssp += __shfl_xor(ssp, 1); ssp += __shfl_xor(ssp, 2);
        ssp += __shfl_xor(ssp, 4); ssp += __shfl_xor(ssp, 8);
        twp += __shfl_xor(twp, 1); twp += __shfl_xor(twp, 2);
        twp += __shfl_xor(twp, 4); twp += __shfl_xor(twp, 8);
        if (vote) {
            vwp += __shfl_xor(vwp, 1); vwp += __shfl_xor(vwp, 2);
            vwp += __shfl_xor(vwp, 4); vwp += __shfl_xor(vwp, 8);
        }
        if (m == 0) {
            int rl = rw * 16 + g * 4 + r;
            ssx[rl * 2 + nh] = ssp;
            twx[rl * 2 + nh] = twp;
            if (vote) vwx[rl * 2 + nh] = vwp;
        }
    }
    __syncthreads();                                   // b4
    const float vb0 = vote ? vb[0] : 0.f;
    #pragma unroll
    for (int r = 0; r < 4; r++) {
        const int rl = rw * 16 + g * 4 + r;
        const int grow = lbase + perm[lbase + rl];
        const float ss = ssx[rl * 2] + ssx[rl * 2 + 1];
        const float rn = __builtin_amdgcn_rsqf(ss);
        const size_t rowoff = (size_t)grow * D + m;
        #pragma unroll
        for (int nn = 0; nn < 4; nn++) {
            const float y = wv[r][nn] * rn;
            xl_dst[rowoff + (nbase + nn) * 16] = f2bf(y);
            if (xl_out) xl_out[rowoff + (nbase + nn) * 16] = y;
        }
        if (m == 0 && nh == 0) {
            const float td = rn * (twx[rl * 2] + twx[rl * 2 + 1]);
            truth[grow] = td;
            if (truth2) truth2[grow] = td;
            if (vote) vote[grow] = rn * (vwx[rl * 2] + vwx[rl * 2 + 1]) + vb0;
        }
    }
}

// ---------------- mean-pool --------------------------------------------------
__global__ void pool_kernel(const float* __restrict__ votes, float* __restrict__ pool) {
    __shared__ float s[4];
    int g = blockIdx.x, t = threadIdx.x;
    float v = votes[g * LITS_PER + t] + votes[g * LITS_PER + 256 + t];
    #pragma unroll
    for (int m = 32; m; m >>= 1) v += __shfl_xor(v, m);
    if ((t & 63) == 0) s[t >> 6] = v;
    __syncthreads();
    if (t == 0) pool[g] = (s[0] + s[1] + s[2] + s[3]) * (1.0f / LITS_PER);
}

// ---------------- launch ----------------------------------------------------
extern "C" void kernel_launch(void* const* d_in, const int* in_sizes, int n_in,
                              void* d_out, int out_size, void* d_ws, size_t ws_size,
                              hipStream_t stream) {
    const int*   edge_lit = (const int*)d_in[1];
    const float* x_l0     = (const float*)d_in[2];
    const float* x_c0     = (const float*)d_in[3];
    const float* W_ih_lc  = (const float*)d_in[4];
    const float* W_hh_lc  = (const float*)d_in[5];
    const float* b_ih_lc  = (const float*)d_in[6];
    const float* b_hh_lc  = (const float*)d_in[7];
    const float* W_ih_cl  = (const float*)d_in[8];
    const float* W_hh_cl  = (const float*)d_in[9];
    const float* b_ih_cl  = (const float*)d_in[10];
    const float* b_hh_cl  = (const float*)d_in[11];
    const float* L_vote_w = (const float*)d_in[12];
    const float* L_vote_b = (const float*)d_in[13];
    const float* true_vec = (const float*)d_in[14];
    // d_in[15] = num_iters (=8, compile-time T)

    float* out   = (float*)d_out;
    float* xl_o  = out + OFF_XL;
    float* call  = out + OFF_CALL;
    float* tall  = out + OFF_TALL;

    // workspace (16B-aligned slices)
    unsigned short* xc_bf  = (unsigned short*)d_ws;          // NC*D bf16
    unsigned short* xl_bf0 = xc_bf + (size_t)NC * D;         // NL*D bf16
    unsigned short* xl_bf1 = xl_bf0 + (size_t)NL * D;        // NL*D bf16
    unsigned short* pk     = xl_bf1 + (size_t)NL * D;        // PK_TOT
    float* norms = (float*)(pk + PK_TOT);                    // NC
    int* counts = (int*)(norms + NC);                        // NL
    int* offs   = counts + NL;                               // NL+1
    int* cursor = offs + NL + 1;                             // NL
    int* csr    = cursor + NL;                               // NE
    int* perm   = csr + NE;                                  // NL

    hipMemsetAsync(counts, 0, NL * sizeof(int), stream);

    pack5<<<PK_TOT / 256, 256, 0, stream>>>(W_ih_lc, W_hh_lc, W_hh_cl, W_ih_cl, pk);
    csr_count<<<NE / 256, 256, 0, stream>>>(edge_lit, counts);
    csr_scan<<<1, 1024, 0, stream>>>(counts, offs, cursor);
    csr_fill<<<NE / 256, 256, 0, stream>>>(edge_lit, cursor, csr);
    csr_sort<<<NL / 256, 256, 0, stream>>>(offs, csr);
    make_perm<<<NL / 64, 64, 0, stream>>>(counts, perm);

    // init: x_l -> normalized f32 (slot) + bf16 (xl_bf0) + truth0;
    //       x_c -> normalized f32 (call slice 0) + raw bf16 + norms
    rownorm_dot<<<NL / 4, 256, 0, stream>>>(x_l0, xl_o, xl_bf0, nullptr, true_vec,
                                            tall, out + OFF_T0, NL);
    rownorm_dot<<<NC / 4, 256, 0, stream>>>(x_c0, call, xc_bf, norms, nullptr,
                                            nullptr, nullptr, NC);

    for (int t = 1; t <= T; t++) {
        const unsigned short* src = (t & 1) ? xl_bf0 : xl_bf1;
        unsigned short*       dst = (t & 1) ? xl_bf1 : xl_bf0;
        lc_mfma<<<NC / 128, 512, SHM_LC, stream>>>(
            edge_lit, src, xc_bf, norms, pk, b_ih_lc, b_hh_lc,
            call + (size_t)t * NC * D);
        cl_mfma<<<NL / 64, 512, SHM_CL, stream>>>(
            offs, csr, perm, xc_bf, src, pk,
            b_ih_cl, b_hh_cl, true_vec, L_vote_w, L_vote_b,
            dst, (t == T) ? xl_o : nullptr, tall + (size_t)t * NL,
            (t == T) ? out + OFF_TLAST : nullptr,
            (t == T) ? out + OFF_VOTE : nullptr);
    }

    pool_kernel<<<Bg, 256, 0, stream>>>(out + OFF_VOTE, out + OFF_POOL);
}